// Round 1
// baseline (5118.008 us; speedup 1.0000x reference)
//
#include <hip/hip_runtime.h>
#include <hip/hip_bf16.h>

// Problem constants (fixed by the reference setup_inputs()):
#define N_R   50000
#define N_V   2000
#define DIM   128
#define E_RR  800000
#define NLAY  3
#define NGR   32

// ---------------------------------------------------------------------------
// Combine W_root[l,0] + W_root[l,2]  (both apply to x_r in the same layer)
__global__ __launch_bounds__(256) void combine_w_kernel(
    const float* __restrict__ Wroot, float* __restrict__ Wc)
{
    int idx = blockIdx.x * 256 + threadIdx.x;           // over NLAY*DIM*DIM
    if (idx >= NLAY * DIM * DIM) return;
    int l = idx / (DIM * DIM);
    int rest = idx - l * DIM * DIM;
    const float* base = Wroot + (size_t)l * 3 * DIM * DIM;
    Wc[idx] = base[rest] + base[2 * DIM * DIM + rest];
}

__global__ __launch_bounds__(256) void combine_b_kernel(
    const float* __restrict__ bias, float* __restrict__ bc)
{
    int idx = blockIdx.x * 256 + threadIdx.x;           // over NLAY*DIM
    if (idx >= NLAY * DIM) return;
    int l = idx / DIM;
    int rest = idx - l * DIM;
    const float* base = bias + (size_t)l * 3 * DIM;
    bc[idx] = base[rest] + base[2 * DIM + rest];
}

// ---------------------------------------------------------------------------
// Scatter-add: accum[dst[e]] += x[src[e]]   (one edge handled by 32 threads,
// each thread does a float4 slice -> 4 scalar atomics)
__global__ __launch_bounds__(256) void scatter_kernel(
    const int* __restrict__ src, const int* __restrict__ dst,
    const float* __restrict__ x, float* __restrict__ accum, int nedges)
{
    int idx = blockIdx.x * 256 + threadIdx.x;
    int e = idx >> 5;
    if (e >= nedges) return;
    int c4 = (idx & 31) << 2;
    int s = src[e];
    int d = dst[e];
    float4 v = *(const float4*)(x + (size_t)s * DIM + c4);
    float* a = accum + (size_t)d * DIM + c4;
    atomicAdd(a + 0, v.x);
    atomicAdd(a + 1, v.y);
    atomicAdd(a + 2, v.z);
    atomicAdd(a + 3, v.w);
}

// ---------------------------------------------------------------------------
// Generic fused GEMM:
//   out[i][:] = [relu]( A[i] @ WA  (+ B[i] @ WB)  (+ gatherTab[gatherIdx[i]])
//                       (+ bias) )
// 8 rows per 256-thread block; each thread produces 4 contiguous columns.
__global__ __launch_bounds__(256) void gemm_kernel(
    const float* __restrict__ A,  const float* __restrict__ WA,
    const float* __restrict__ B,  const float* __restrict__ WB,
    const float* __restrict__ gatherTab, const int* __restrict__ gatherIdx,
    const float* __restrict__ bias, float* __restrict__ out,
    int nrows, int doRelu)
{
    int t = threadIdx.x;
    int localRow = t >> 5;            // 0..7
    int j4 = (t & 31) << 2;           // column start 0..124
    int row = blockIdx.x * 8 + localRow;
    if (row >= nrows) return;

    float4 acc = make_float4(0.f, 0.f, 0.f, 0.f);
    const float* arow = A + (size_t)row * DIM;

    if (B != nullptr) {
        const float* brow = B + (size_t)row * DIM;
        #pragma unroll 8
        for (int k = 0; k < DIM; ++k) {
            float av = arow[k];
            float bv = brow[k];
            float4 wa = *(const float4*)(WA + (size_t)k * DIM + j4);
            float4 wb = *(const float4*)(WB + (size_t)k * DIM + j4);
            acc.x += av * wa.x + bv * wb.x;
            acc.y += av * wa.y + bv * wb.y;
            acc.z += av * wa.z + bv * wb.z;
            acc.w += av * wa.w + bv * wb.w;
        }
    } else {
        #pragma unroll 8
        for (int k = 0; k < DIM; ++k) {
            float av = arow[k];
            float4 wa = *(const float4*)(WA + (size_t)k * DIM + j4);
            acc.x += av * wa.x;
            acc.y += av * wa.y;
            acc.z += av * wa.z;
            acc.w += av * wa.w;
        }
    }

    if (gatherTab != nullptr) {
        int g = gatherIdx[row];
        float4 tv = *(const float4*)(gatherTab + (size_t)g * DIM + j4);
        acc.x += tv.x; acc.y += tv.y; acc.z += tv.z; acc.w += tv.w;
    }
    if (bias != nullptr) {
        float4 b = *(const float4*)(bias + j4);
        acc.x += b.x; acc.y += b.y; acc.z += b.z; acc.w += b.w;
    }
    if (doRelu) {
        acc.x = fmaxf(acc.x, 0.f);
        acc.y = fmaxf(acc.y, 0.f);
        acc.z = fmaxf(acc.z, 0.f);
        acc.w = fmaxf(acc.w, 0.f);
    }
    *(float4*)(out + (size_t)row * DIM + j4) = acc;
}

// ---------------------------------------------------------------------------
// Readout: per-graph mean over real nodes. batch is sorted, so run-length
// accumulate locally and flush with one atomic per (block, graph) boundary.
__global__ __launch_bounds__(128) void readout_kernel(
    const float* __restrict__ xr, const int* __restrict__ batch,
    float* __restrict__ gsum, float* __restrict__ gcnt,
    int nrows, int rowsPerBlock)
{
    int c = threadIdx.x;                  // 0..127 (one column per thread)
    int r0 = blockIdx.x * rowsPerBlock;
    if (r0 >= nrows) return;
    int r1 = min(r0 + rowsPerBlock, nrows);

    int cur = batch[r0];
    float local = 0.f;
    float cnt = 0.f;
    for (int i = r0; i < r1; ++i) {
        int g = batch[i];
        if (g != cur) {
            atomicAdd(&gsum[(size_t)cur * DIM + c], local);
            if (c == 0) atomicAdd(&gcnt[cur], cnt);
            local = 0.f; cnt = 0.f; cur = g;
        }
        local += xr[(size_t)i * DIM + c];
        cnt += 1.f;
    }
    atomicAdd(&gsum[(size_t)cur * DIM + c], local);
    if (c == 0) atomicAdd(&gcnt[cur], cnt);
}

__global__ __launch_bounds__(256) void finalize_kernel(
    const float* __restrict__ gsum, const float* __restrict__ gcnt,
    float* __restrict__ out)
{
    int idx = blockIdx.x * 256 + threadIdx.x;   // over NGR*DIM
    if (idx >= NGR * DIM) return;
    int g = idx >> 7;
    out[idx] = gsum[idx] / fmaxf(gcnt[g], 1.f);
}

// ---------------------------------------------------------------------------
extern "C" void kernel_launch(void* const* d_in, const int* in_sizes, int n_in,
                              void* d_out, int out_size, void* d_ws, size_t ws_size,
                              hipStream_t stream)
{
    const float* x_real    = (const float*)d_in[0];
    const float* x_virtual = (const float*)d_in[1];
    const float* W_root    = (const float*)d_in[2];
    const float* W_nbr     = (const float*)d_in[3];
    const float* bias      = (const float*)d_in[4];
    const int*   edge_rr   = (const int*)d_in[5];   // [2, E_RR]
    const int*   edge_rv   = (const int*)d_in[6];   // [2, N_R]  row0=arange, row1=vmap
    const int*   edge_vr   = (const int*)d_in[7];   // [2, N_R]  row0=vmap,  row1=arange
    const int*   batch     = (const int*)d_in[8];   // [N_R] sorted

    float* out = (float*)d_out;                     // [N_R*DIM] + [NGR*DIM]

    // workspace layout (floats)
    float* ws   = (float*)d_ws;
    float* xr_a = ws;                      // N_R*DIM
    float* xr_b = xr_a + (size_t)N_R * DIM;
    float* Arr  = xr_b + (size_t)N_R * DIM;
    float* xv_a = Arr  + (size_t)N_R * DIM;
    float* xv_b = xv_a + (size_t)N_V * DIM;
    float* Arv  = xv_b + (size_t)N_V * DIM;
    float* Tv   = Arv  + (size_t)N_V * DIM;
    float* Wc   = Tv   + (size_t)N_V * DIM;        // NLAY*DIM*DIM
    float* bc   = Wc   + (size_t)NLAY * DIM * DIM; // NLAY*DIM
    float* gsum = bc   + (size_t)NLAY * DIM;       // NGR*DIM
    float* gcnt = gsum + (size_t)NGR * DIM;        // NGR

    // precombine root weights/biases for the real-node update
    combine_w_kernel<<<(NLAY * DIM * DIM + 255) / 256, 256, 0, stream>>>(W_root, Wc);
    combine_b_kernel<<<(NLAY * DIM + 255) / 256, 256, 0, stream>>>(bias, bc);

    const float* cur_xr = x_real;
    const float* cur_xv = x_virtual;

    for (int l = 0; l < NLAY; ++l) {
        const float* Wn0 = W_nbr + ((size_t)l * 3 + 0) * DIM * DIM;  // r->r nbr
        const float* Wn1 = W_nbr + ((size_t)l * 3 + 1) * DIM * DIM;  // r->v nbr
        const float* Wn2 = W_nbr + ((size_t)l * 3 + 2) * DIM * DIM;  // v->r nbr
        const float* Wr1 = W_root + ((size_t)l * 3 + 1) * DIM * DIM; // v root
        const float* b1  = bias + ((size_t)l * 3 + 1) * DIM;

        // A_rr = segment_sum(x_r[src], dst)  over r->r edges
        hipMemsetAsync(Arr, 0, (size_t)N_R * DIM * sizeof(float), stream);
        scatter_kernel<<<(E_RR * 32) / 256, 256, 0, stream>>>(
            edge_rr, edge_rr + E_RR, cur_xr, Arr, E_RR);

        // T_v = x_v @ W_nbr[l,2]  (v->r messages per virtual node)
        gemm_kernel<<<(N_V + 7) / 8, 256, 0, stream>>>(
            cur_xv, Wn2, nullptr, nullptr, nullptr, nullptr, nullptr, Tv, N_V, 0);

        // x_r_new = relu( x_r @ (Wr0+Wr2) + A_rr @ Wn0 + T_v[vmap] + (b0+b2) )
        float* xr_out = (l == NLAY - 1) ? out : ((l & 1) ? xr_b : xr_a);
        gemm_kernel<<<(N_R + 7) / 8, 256, 0, stream>>>(
            cur_xr, Wc + (size_t)l * DIM * DIM,
            Arr, Wn0,
            Tv, edge_vr,                 // gather T_v[edge_vr[0][i]]
            bc + (size_t)l * DIM,
            xr_out, N_R, 1);

        if (l < NLAY - 1) {
            // A_rv = segment_sum(x_r[src], vmap)   (uses layer-INPUT x_r)
            hipMemsetAsync(Arv, 0, (size_t)N_V * DIM * sizeof(float), stream);
            scatter_kernel<<<(N_R * 32) / 256, 256, 0, stream>>>(
                edge_rv, edge_rv + N_R, cur_xr, Arv, N_R);

            // x_v_new = relu( x_v @ Wr1 + A_rv @ Wn1 + b1 )
            float* xv_out = (l & 1) ? xv_b : xv_a;
            gemm_kernel<<<(N_V + 7) / 8, 256, 0, stream>>>(
                cur_xv, Wr1, Arv, Wn1, nullptr, nullptr, b1, xv_out, N_V, 1);
            cur_xv = xv_out;
        }
        cur_xr = xr_out;
    }

    // readout: mean over real nodes per graph
    hipMemsetAsync(gsum, 0, (size_t)NGR * DIM * sizeof(float), stream);
    hipMemsetAsync(gcnt, 0, (size_t)NGR * sizeof(float), stream);
    const int rowsPerBlock = 256;
    readout_kernel<<<(N_R + rowsPerBlock - 1) / rowsPerBlock, 128, 0, stream>>>(
        out, batch, gsum, gcnt, N_R, rowsPerBlock);
    finalize_kernel<<<(NGR * DIM + 255) / 256, 256, 0, stream>>>(
        gsum, gcnt, out + (size_t)N_R * DIM);
}

// Round 2
// 1294.202 us; speedup vs baseline: 3.9546x; 3.9546x over previous
//
#include <hip/hip_runtime.h>
#include <hip/hip_bf16.h>

// Problem constants (fixed by the reference setup_inputs()):
#define N_R   50000
#define N_V   2000
#define DIM   128
#define E_RR  800000
#define NLAY  3
#define NGR   32

// ---------------------------------------------------------------------------
// CSR build: histogram -> single-block scan -> fill
__global__ __launch_bounds__(256) void hist_kernel(
    const int* __restrict__ dst, int n, int* __restrict__ cnt)
{
    int i = blockIdx.x * 256 + threadIdx.x;
    if (i < n) atomicAdd(&cnt[dst[i]], 1);
}

__global__ __launch_bounds__(1024) void scan_kernel(
    const int* __restrict__ cnt, int nbins, int nedges,
    int* __restrict__ rowptr, int* __restrict__ cursor)
{
    __shared__ int lds[1024];
    int t = threadIdx.x;
    int C = (nbins + 1023) >> 10;
    int b0 = t * C, b1 = min(b0 + C, nbins);
    int s = 0;
    for (int i = b0; i < b1; ++i) s += cnt[i];
    lds[t] = s;
    __syncthreads();
    // Hillis-Steele inclusive scan over 1024 partials
    for (int off = 1; off < 1024; off <<= 1) {
        int v = (t >= off) ? lds[t - off] : 0;
        __syncthreads();
        lds[t] += v;
        __syncthreads();
    }
    int run = (t == 0) ? 0 : lds[t - 1];
    for (int i = b0; i < b1; ++i) {
        rowptr[i] = run;
        cursor[i] = run;
        run += cnt[i];
    }
    if (t == 0) rowptr[nbins] = nedges;
}

__global__ __launch_bounds__(256) void fill_kernel(
    const int* __restrict__ src, const int* __restrict__ dst, int n,
    int* __restrict__ cursor, int* __restrict__ col)
{
    int i = blockIdx.x * 256 + threadIdx.x;
    if (i < n) {
        int p = atomicAdd(&cursor[dst[i]], 1);
        col[p] = src[i];
    }
}

// ---------------------------------------------------------------------------
// Gather-aggregate: out[d][:] = sum over CSR segment of x[col[i]][:]
// One 64-lane wave per destination row; each lane owns 2 columns (float2).
__global__ __launch_bounds__(256) void agg_kernel(
    const int* __restrict__ rowptr, const int* __restrict__ col,
    const float* __restrict__ x, float* __restrict__ out, int nrows)
{
    int gid = blockIdx.x * 256 + threadIdx.x;
    int w = gid >> 6;
    int lane = gid & 63;
    if (w >= nrows) return;
    int beg = rowptr[w], end = rowptr[w + 1];
    float2 acc = make_float2(0.f, 0.f);
    int i = beg;
    // 2-way unroll to keep two gathers in flight
    for (; i + 1 < end; i += 2) {
        int s0 = col[i], s1 = col[i + 1];
        float2 v0 = *(const float2*)(x + (size_t)s0 * DIM + lane * 2);
        float2 v1 = *(const float2*)(x + (size_t)s1 * DIM + lane * 2);
        acc.x += v0.x + v1.x;
        acc.y += v0.y + v1.y;
    }
    if (i < end) {
        int s0 = col[i];
        float2 v0 = *(const float2*)(x + (size_t)s0 * DIM + lane * 2);
        acc.x += v0.x;
        acc.y += v0.y;
    }
    *(float2*)(out + (size_t)w * DIM + lane * 2) = acc;
}

// ---------------------------------------------------------------------------
// Combine W_root[l,0] + W_root[l,2]  (both apply to x_r in the same layer)
__global__ __launch_bounds__(256) void combine_w_kernel(
    const float* __restrict__ Wroot, float* __restrict__ Wc)
{
    int idx = blockIdx.x * 256 + threadIdx.x;           // over NLAY*DIM*DIM
    if (idx >= NLAY * DIM * DIM) return;
    int l = idx / (DIM * DIM);
    int rest = idx - l * DIM * DIM;
    const float* base = Wroot + (size_t)l * 3 * DIM * DIM;
    Wc[idx] = base[rest] + base[2 * DIM * DIM + rest];
}

__global__ __launch_bounds__(256) void combine_b_kernel(
    const float* __restrict__ bias, float* __restrict__ bc)
{
    int idx = blockIdx.x * 256 + threadIdx.x;           // over NLAY*DIM
    if (idx >= NLAY * DIM) return;
    int l = idx / DIM;
    int rest = idx - l * DIM;
    const float* base = bias + (size_t)l * 3 * DIM;
    bc[idx] = base[rest] + base[2 * DIM + rest];
}

// ---------------------------------------------------------------------------
// Generic fused GEMM:
//   out[i][:] = [relu]( A[i] @ WA  (+ B[i] @ WB)  (+ gatherTab[gatherIdx[i]])
//                       (+ bias) )
// 8 rows per 256-thread block; each thread produces 4 contiguous columns.
__global__ __launch_bounds__(256) void gemm_kernel(
    const float* __restrict__ A,  const float* __restrict__ WA,
    const float* __restrict__ B,  const float* __restrict__ WB,
    const float* __restrict__ gatherTab, const int* __restrict__ gatherIdx,
    const float* __restrict__ bias, float* __restrict__ out,
    int nrows, int doRelu)
{
    int t = threadIdx.x;
    int localRow = t >> 5;            // 0..7
    int j4 = (t & 31) << 2;           // column start 0..124
    int row = blockIdx.x * 8 + localRow;
    if (row >= nrows) return;

    float4 acc = make_float4(0.f, 0.f, 0.f, 0.f);
    const float* arow = A + (size_t)row * DIM;

    if (B != nullptr) {
        const float* brow = B + (size_t)row * DIM;
        #pragma unroll 8
        for (int k = 0; k < DIM; ++k) {
            float av = arow[k];
            float bv = brow[k];
            float4 wa = *(const float4*)(WA + (size_t)k * DIM + j4);
            float4 wb = *(const float4*)(WB + (size_t)k * DIM + j4);
            acc.x += av * wa.x + bv * wb.x;
            acc.y += av * wa.y + bv * wb.y;
            acc.z += av * wa.z + bv * wb.z;
            acc.w += av * wa.w + bv * wb.w;
        }
    } else {
        #pragma unroll 8
        for (int k = 0; k < DIM; ++k) {
            float av = arow[k];
            float4 wa = *(const float4*)(WA + (size_t)k * DIM + j4);
            acc.x += av * wa.x;
            acc.y += av * wa.y;
            acc.z += av * wa.z;
            acc.w += av * wa.w;
        }
    }

    if (gatherTab != nullptr) {
        int g = gatherIdx[row];
        float4 tv = *(const float4*)(gatherTab + (size_t)g * DIM + j4);
        acc.x += tv.x; acc.y += tv.y; acc.z += tv.z; acc.w += tv.w;
    }
    if (bias != nullptr) {
        float4 b = *(const float4*)(bias + j4);
        acc.x += b.x; acc.y += b.y; acc.z += b.z; acc.w += b.w;
    }
    if (doRelu) {
        acc.x = fmaxf(acc.x, 0.f);
        acc.y = fmaxf(acc.y, 0.f);
        acc.z = fmaxf(acc.z, 0.f);
        acc.w = fmaxf(acc.w, 0.f);
    }
    *(float4*)(out + (size_t)row * DIM + j4) = acc;
}

// ---------------------------------------------------------------------------
// Readout: per-graph mean over real nodes. batch is sorted, so run-length
// accumulate locally and flush with one atomic per (block, graph) boundary.
__global__ __launch_bounds__(128) void readout_kernel(
    const float* __restrict__ xr, const int* __restrict__ batch,
    float* __restrict__ gsum, float* __restrict__ gcnt,
    int nrows, int rowsPerBlock)
{
    int c = threadIdx.x;                  // 0..127 (one column per thread)
    int r0 = blockIdx.x * rowsPerBlock;
    if (r0 >= nrows) return;
    int r1 = min(r0 + rowsPerBlock, nrows);

    int cur = batch[r0];
    float local = 0.f;
    float cnt = 0.f;
    for (int i = r0; i < r1; ++i) {
        int g = batch[i];
        if (g != cur) {
            atomicAdd(&gsum[(size_t)cur * DIM + c], local);
            if (c == 0) atomicAdd(&gcnt[cur], cnt);
            local = 0.f; cnt = 0.f; cur = g;
        }
        local += xr[(size_t)i * DIM + c];
        cnt += 1.f;
    }
    atomicAdd(&gsum[(size_t)cur * DIM + c], local);
    if (c == 0) atomicAdd(&gcnt[cur], cnt);
}

__global__ __launch_bounds__(256) void finalize_kernel(
    const float* __restrict__ gsum, const float* __restrict__ gcnt,
    float* __restrict__ out)
{
    int idx = blockIdx.x * 256 + threadIdx.x;   // over NGR*DIM
    if (idx >= NGR * DIM) return;
    int g = idx >> 7;
    out[idx] = gsum[idx] / fmaxf(gcnt[g], 1.f);
}

// ---------------------------------------------------------------------------
extern "C" void kernel_launch(void* const* d_in, const int* in_sizes, int n_in,
                              void* d_out, int out_size, void* d_ws, size_t ws_size,
                              hipStream_t stream)
{
    const float* x_real    = (const float*)d_in[0];
    const float* x_virtual = (const float*)d_in[1];
    const float* W_root    = (const float*)d_in[2];
    const float* W_nbr     = (const float*)d_in[3];
    const float* bias      = (const float*)d_in[4];
    const int*   edge_rr   = (const int*)d_in[5];   // [2, E_RR]
    const int*   edge_rv   = (const int*)d_in[6];   // [2, N_R]  row0=arange, row1=vmap
    const int*   edge_vr   = (const int*)d_in[7];   // [2, N_R]  row0=vmap,  row1=arange
    const int*   batch     = (const int*)d_in[8];   // [N_R] sorted

    float* out = (float*)d_out;                     // [N_R*DIM] + [NGR*DIM]

    // ---- workspace layout ----
    float* ws   = (float*)d_ws;
    float* xr_a = ws;                      // N_R*DIM
    float* xr_b = xr_a + (size_t)N_R * DIM;
    float* Arr  = xr_b + (size_t)N_R * DIM;
    float* xv_a = Arr  + (size_t)N_R * DIM;
    float* xv_b = xv_a + (size_t)N_V * DIM;
    float* Arv  = xv_b + (size_t)N_V * DIM;
    float* Tv   = Arv  + (size_t)N_V * DIM;
    float* Wc   = Tv   + (size_t)N_V * DIM;        // NLAY*DIM*DIM
    float* bc   = Wc   + (size_t)NLAY * DIM * DIM; // NLAY*DIM
    float* gsum = bc   + (size_t)NLAY * DIM;       // NGR*DIM
    float* gcnt = gsum + (size_t)NGR * DIM;        // NGR
    int*   iws        = (int*)(gcnt + NGR);
    int*   cnt_r      = iws;                        // N_R
    int*   rowptr_rr  = cnt_r + N_R;                // N_R+1
    int*   cursor_rr  = rowptr_rr + N_R + 1;        // N_R
    int*   col_rr     = cursor_rr + N_R;            // E_RR
    int*   cnt_v      = col_rr + E_RR;              // N_V
    int*   rowptr_rv  = cnt_v + N_V;                // N_V+1
    int*   cursor_rv  = rowptr_rv + N_V + 1;        // N_V
    int*   col_rv     = cursor_rv + N_V;            // N_R

    // ---- build CSR (by destination) for r->r and r->v; reused across layers
    const int* rr_src = edge_rr;
    const int* rr_dst = edge_rr + E_RR;
    const int* rv_src = edge_rv;            // arange
    const int* rv_dst = edge_rv + N_R;      // vmap

    hipMemsetAsync(cnt_r, 0, (size_t)N_R * sizeof(int), stream);
    hipMemsetAsync(cnt_v, 0, (size_t)N_V * sizeof(int), stream);
    hist_kernel<<<(E_RR + 255) / 256, 256, 0, stream>>>(rr_dst, E_RR, cnt_r);
    hist_kernel<<<(N_R + 255) / 256, 256, 0, stream>>>(rv_dst, N_R, cnt_v);
    scan_kernel<<<1, 1024, 0, stream>>>(cnt_r, N_R, E_RR, rowptr_rr, cursor_rr);
    scan_kernel<<<1, 1024, 0, stream>>>(cnt_v, N_V, N_R, rowptr_rv, cursor_rv);
    fill_kernel<<<(E_RR + 255) / 256, 256, 0, stream>>>(rr_src, rr_dst, E_RR, cursor_rr, col_rr);
    fill_kernel<<<(N_R + 255) / 256, 256, 0, stream>>>(rv_src, rv_dst, N_R, cursor_rv, col_rv);

    // precombine root weights/biases for the real-node update
    combine_w_kernel<<<(NLAY * DIM * DIM + 255) / 256, 256, 0, stream>>>(W_root, Wc);
    combine_b_kernel<<<(NLAY * DIM + 255) / 256, 256, 0, stream>>>(bias, bc);

    const float* cur_xr = x_real;
    const float* cur_xv = x_virtual;

    for (int l = 0; l < NLAY; ++l) {
        const float* Wn0 = W_nbr + ((size_t)l * 3 + 0) * DIM * DIM;  // r->r nbr
        const float* Wn1 = W_nbr + ((size_t)l * 3 + 1) * DIM * DIM;  // r->v nbr
        const float* Wn2 = W_nbr + ((size_t)l * 3 + 2) * DIM * DIM;  // v->r nbr
        const float* Wr1 = W_root + ((size_t)l * 3 + 1) * DIM * DIM; // v root
        const float* b1  = bias + ((size_t)l * 3 + 1) * DIM;

        // A_rr[d] = sum_{e: dst=d} x_r[src[e]]   (gather-aggregate, no atomics)
        agg_kernel<<<(N_R * 64 + 255) / 256, 256, 0, stream>>>(
            rowptr_rr, col_rr, cur_xr, Arr, N_R);

        // T_v = x_v @ W_nbr[l,2]  (v->r messages per virtual node)
        gemm_kernel<<<(N_V + 7) / 8, 256, 0, stream>>>(
            cur_xv, Wn2, nullptr, nullptr, nullptr, nullptr, nullptr, Tv, N_V, 0);

        // x_r_new = relu( x_r @ (Wr0+Wr2) + A_rr @ Wn0 + T_v[vmap] + (b0+b2) )
        float* xr_out = (l == NLAY - 1) ? out : ((l & 1) ? xr_b : xr_a);
        gemm_kernel<<<(N_R + 7) / 8, 256, 0, stream>>>(
            cur_xr, Wc + (size_t)l * DIM * DIM,
            Arr, Wn0,
            Tv, edge_vr,                 // gather T_v[edge_vr[0][i]] (= vmap[i])
            bc + (size_t)l * DIM,
            xr_out, N_R, 1);

        if (l < NLAY - 1) {
            // A_rv[v] = sum_{r: vmap[r]=v} x_r[r]   (uses layer-INPUT x_r)
            agg_kernel<<<(N_V * 64 + 255) / 256, 256, 0, stream>>>(
                rowptr_rv, col_rv, cur_xr, Arv, N_V);

            // x_v_new = relu( x_v @ Wr1 + A_rv @ Wn1 + b1 )
            float* xv_out = (l & 1) ? xv_b : xv_a;
            gemm_kernel<<<(N_V + 7) / 8, 256, 0, stream>>>(
                cur_xv, Wr1, Arv, Wn1, nullptr, nullptr, b1, xv_out, N_V, 1);
            cur_xv = xv_out;
        }
        cur_xr = xr_out;
    }

    // readout: mean over real nodes per graph
    hipMemsetAsync(gsum, 0, (size_t)NGR * DIM * sizeof(float), stream);
    hipMemsetAsync(gcnt, 0, (size_t)NGR * sizeof(float), stream);
    const int rowsPerBlock = 256;
    readout_kernel<<<(N_R + rowsPerBlock - 1) / rowsPerBlock, 128, 0, stream>>>(
        out, batch, gsum, gcnt, N_R, rowsPerBlock);
    finalize_kernel<<<(NGR * DIM + 255) / 256, 256, 0, stream>>>(
        gsum, gcnt, out + (size_t)N_R * DIM);
}

// Round 3
// 695.757 us; speedup vs baseline: 7.3560x; 1.8601x over previous
//
#include <hip/hip_runtime.h>
#include <hip/hip_bf16.h>

// Problem constants (fixed by the reference setup_inputs()):
#define N_R   50000
#define N_V   2000
#define DIM   128
#define E_RR  800000
#define NLAY  3
#define NGR   32

typedef __attribute__((ext_vector_type(8))) short bf16x8;
typedef __attribute__((ext_vector_type(4))) float f32x4;

__device__ __forceinline__ ushort f2bf(float f) {
    unsigned u = __builtin_bit_cast(unsigned, f);
    unsigned r = (u + 0x7fffu + ((u >> 16) & 1u)) >> 16;   // RNE
    return (ushort)r;
}
__device__ __forceinline__ float bf2f(ushort h) {
    unsigned u = ((unsigned)h) << 16;
    return __builtin_bit_cast(float, u);
}

// ---------------------------------------------------------------------------
// CSR build: histogram -> single-block scan -> fill
__global__ __launch_bounds__(256) void hist_kernel(
    const int* __restrict__ dst, int n, int* __restrict__ cnt)
{
    int i = blockIdx.x * 256 + threadIdx.x;
    if (i < n) atomicAdd(&cnt[dst[i]], 1);
}

__global__ __launch_bounds__(1024) void scan_kernel(
    const int* __restrict__ cnt, int nbins, int nedges,
    int* __restrict__ rowptr, int* __restrict__ cursor)
{
    __shared__ int lds[1024];
    int t = threadIdx.x;
    int C = (nbins + 1023) >> 10;
    int b0 = t * C, b1 = min(b0 + C, nbins);
    int s = 0;
    for (int i = b0; i < b1; ++i) s += cnt[i];
    lds[t] = s;
    __syncthreads();
    for (int off = 1; off < 1024; off <<= 1) {
        int v = (t >= off) ? lds[t - off] : 0;
        __syncthreads();
        lds[t] += v;
        __syncthreads();
    }
    int run = (t == 0) ? 0 : lds[t - 1];
    for (int i = b0; i < b1; ++i) {
        rowptr[i] = run;
        cursor[i] = run;
        run += cnt[i];
    }
    if (t == 0) rowptr[nbins] = nedges;
}

__global__ __launch_bounds__(256) void fill_kernel(
    const int* __restrict__ src, const int* __restrict__ dst, int n,
    int* __restrict__ cursor, int* __restrict__ col)
{
    int i = blockIdx.x * 256 + threadIdx.x;
    if (i < n) {
        int p = atomicAdd(&cursor[dst[i]], 1);
        col[p] = src[i];
    }
}

// ---------------------------------------------------------------------------
// Convert fp32 matrix to bf16
__global__ __launch_bounds__(256) void conv_bf16_kernel(
    const float* __restrict__ in, ushort* __restrict__ out, int n4)
{
    int i = blockIdx.x * 256 + threadIdx.x;      // over n/4
    if (i >= n4) return;
    float4 v = *(const float4*)(in + (size_t)i * 4);
    ushort4 o;
    o.x = f2bf(v.x); o.y = f2bf(v.y); o.z = f2bf(v.z); o.w = f2bf(v.w);
    *(ushort4*)(out + (size_t)i * 4) = o;
}

// ---------------------------------------------------------------------------
// Build per-layer bf16 weight blocks, n-major:
//   WT[l][n][k] : k<128 -> Wroot[l,0,k,n]+Wroot[l,2,k,n] ; k>=128 -> Wnbr[l,0,k-128,n]
__global__ __launch_bounds__(256) void build_wt_kernel(
    const float* __restrict__ Wroot, const float* __restrict__ Wnbr,
    ushort* __restrict__ WT)
{
    int idx = blockIdx.x * 256 + threadIdx.x;    // over NLAY*128*256
    if (idx >= NLAY * DIM * 2 * DIM) return;
    int k = idx & 255;
    int n = (idx >> 8) & 127;
    int l = idx >> 15;
    float v;
    if (k < DIM) {
        const float* base = Wroot + (size_t)l * 3 * DIM * DIM;
        v = base[(size_t)k * DIM + n] + base[(size_t)(2 * DIM + k) * DIM + n];
    } else {
        v = Wnbr[((size_t)l * 3 * DIM + (k - DIM)) * DIM + n];
    }
    WT[idx] = f2bf(v);
}

__global__ __launch_bounds__(256) void combine_b_kernel(
    const float* __restrict__ bias, float* __restrict__ bc)
{
    int idx = blockIdx.x * 256 + threadIdx.x;           // over NLAY*DIM
    if (idx >= NLAY * DIM) return;
    int l = idx / DIM;
    int rest = idx - l * DIM;
    const float* base = bias + (size_t)l * 3 * DIM;
    bc[idx] = base[rest] + base[2 * DIM + rest];
}

// ---------------------------------------------------------------------------
// Gather-aggregate over bf16 features: out[d][:] = sum x[col[i]][:]
// One wave per destination row; lane owns 2 columns (one dword).
// outB!=null -> write bf16 ; outF!=null -> write fp32
__global__ __launch_bounds__(256) void agg_kernel(
    const int* __restrict__ rowptr, const int* __restrict__ col,
    const ushort* __restrict__ x, ushort* __restrict__ outB,
    float* __restrict__ outF, int nrows)
{
    int gid = blockIdx.x * 256 + threadIdx.x;
    int w = gid >> 6;
    int lane = gid & 63;
    if (w >= nrows) return;
    int beg = rowptr[w], end = rowptr[w + 1];
    float ax = 0.f, ay = 0.f;
    int i = beg;
    for (; i + 1 < end; i += 2) {
        int s0 = col[i], s1 = col[i + 1];
        unsigned v0 = *(const unsigned*)(x + (size_t)s0 * DIM + lane * 2);
        unsigned v1 = *(const unsigned*)(x + (size_t)s1 * DIM + lane * 2);
        ax += bf2f((ushort)(v0 & 0xffff)) + bf2f((ushort)(v1 & 0xffff));
        ay += bf2f((ushort)(v0 >> 16))    + bf2f((ushort)(v1 >> 16));
    }
    if (i < end) {
        unsigned v0 = *(const unsigned*)(x + (size_t)col[i] * DIM + lane * 2);
        ax += bf2f((ushort)(v0 & 0xffff));
        ay += bf2f((ushort)(v0 >> 16));
    }
    if (outB) {
        unsigned o = (unsigned)f2bf(ax) | ((unsigned)f2bf(ay) << 16);
        *(unsigned*)(outB + (size_t)w * DIM + lane * 2) = o;
    }
    if (outF) {
        *(float2*)(outF + (size_t)w * DIM + lane * 2) = make_float2(ax, ay);
    }
}

// ---------------------------------------------------------------------------
// MFMA GEMM for the real-node update:
//   C[M][128] = relu( [A1|A2] @ W  + Tv[vmap[row]]  + bias ),  K = 256
// A1,A2: [M][128] bf16. WT: [128 n][256 k] bf16 (n-major).
// Block: 256 thr = 4 waves; 64 rows/block, wave handles 16 rows x 128 cols.
__global__ __launch_bounds__(256) void mfma_gemm_kernel(
    const ushort* __restrict__ A1, const ushort* __restrict__ A2,
    const ushort* __restrict__ WT, const float* __restrict__ Tv,
    const int* __restrict__ vmap, const float* __restrict__ bias,
    float* __restrict__ outF, ushort* __restrict__ outB, int M)
{
    int wave = threadIdx.x >> 6;
    int lane = threadIdx.x & 63;
    int rlo = lane & 15;          // A-row / B-col / C-col within tile
    int hi = lane >> 4;           // 0..3
    int row0 = blockIdx.x * 64 + wave * 16;
    int arow = row0 + rlo;
    int arowc = min(arow, M - 1);

    // preload 8 A-fragments: frag j covers k = 32j + 8*hi .. +7
    bf16x8 afr[8];
    #pragma unroll
    for (int j = 0; j < 8; ++j) {
        int k = 32 * j + 8 * hi;
        const ushort* src = (k < DIM)
            ? (A1 + (size_t)arowc * DIM + k)
            : (A2 + (size_t)arowc * DIM + (k - DIM));
        afr[j] = *(const bf16x8*)src;
    }

    f32x4 acc[8];
    #pragma unroll
    for (int n = 0; n < 8; ++n) acc[n] = (f32x4){0.f, 0.f, 0.f, 0.f};

    #pragma unroll
    for (int n = 0; n < 8; ++n) {
        const ushort* wrow = WT + (size_t)(n * 16 + rlo) * (2 * DIM);
        #pragma unroll
        for (int j = 0; j < 8; ++j) {
            bf16x8 bfr = *(const bf16x8*)(wrow + 32 * j + 8 * hi);
            acc[n] = __builtin_amdgcn_mfma_f32_16x16x32_bf16(afr[j], bfr, acc[n], 0, 0, 0);
        }
    }

    // epilogue: C row = row0 + 4*hi + i, col = n*16 + rlo
    const float* tvp[4];
    #pragma unroll
    for (int i = 0; i < 4; ++i) {
        int orow = row0 + 4 * hi + i;
        tvp[i] = (Tv != nullptr && orow < M)
                 ? (Tv + (size_t)vmap[orow] * DIM) : nullptr;
    }
    #pragma unroll
    for (int n = 0; n < 8; ++n) {
        int ncol = n * 16 + rlo;
        float bv = bias[ncol];
        #pragma unroll
        for (int i = 0; i < 4; ++i) {
            int orow = row0 + 4 * hi + i;
            if (orow >= M) continue;
            float v = acc[n][i] + bv;
            if (tvp[i]) v += tvp[i][ncol];
            v = fmaxf(v, 0.f);
            if (outF) outF[(size_t)orow * DIM + ncol] = v;
            if (outB) outB[(size_t)orow * DIM + ncol] = f2bf(v);
        }
    }
}

// ---------------------------------------------------------------------------
// Small fp32 GEMM (virtual-node paths, N_V rows):
//   out[i][:] = [relu]( A[i]@WA (+ B[i]@WB) (+ bias) )
__global__ __launch_bounds__(256) void gemm_kernel(
    const float* __restrict__ A,  const float* __restrict__ WA,
    const float* __restrict__ B,  const float* __restrict__ WB,
    const float* __restrict__ bias, float* __restrict__ out,
    int nrows, int doRelu)
{
    int t = threadIdx.x;
    int localRow = t >> 5;
    int j4 = (t & 31) << 2;
    int row = blockIdx.x * 8 + localRow;
    if (row >= nrows) return;

    float4 acc = make_float4(0.f, 0.f, 0.f, 0.f);
    const float* arow = A + (size_t)row * DIM;

    if (B != nullptr) {
        const float* brow = B + (size_t)row * DIM;
        #pragma unroll 8
        for (int k = 0; k < DIM; ++k) {
            float av = arow[k];
            float bv = brow[k];
            float4 wa = *(const float4*)(WA + (size_t)k * DIM + j4);
            float4 wb = *(const float4*)(WB + (size_t)k * DIM + j4);
            acc.x += av * wa.x + bv * wb.x;
            acc.y += av * wa.y + bv * wb.y;
            acc.z += av * wa.z + bv * wb.z;
            acc.w += av * wa.w + bv * wb.w;
        }
    } else {
        #pragma unroll 8
        for (int k = 0; k < DIM; ++k) {
            float av = arow[k];
            float4 wa = *(const float4*)(WA + (size_t)k * DIM + j4);
            acc.x += av * wa.x;
            acc.y += av * wa.y;
            acc.z += av * wa.z;
            acc.w += av * wa.w;
        }
    }
    if (bias != nullptr) {
        float4 b = *(const float4*)(bias + j4);
        acc.x += b.x; acc.y += b.y; acc.z += b.z; acc.w += b.w;
    }
    if (doRelu) {
        acc.x = fmaxf(acc.x, 0.f);
        acc.y = fmaxf(acc.y, 0.f);
        acc.z = fmaxf(acc.z, 0.f);
        acc.w = fmaxf(acc.w, 0.f);
    }
    *(float4*)(out + (size_t)row * DIM + j4) = acc;
}

// ---------------------------------------------------------------------------
// Readout: per-graph mean over real nodes (batch sorted; run-length + atomics)
__global__ __launch_bounds__(128) void readout_kernel(
    const float* __restrict__ xr, const int* __restrict__ batch,
    float* __restrict__ gsum, float* __restrict__ gcnt,
    int nrows, int rowsPerBlock)
{
    int c = threadIdx.x;
    int r0 = blockIdx.x * rowsPerBlock;
    if (r0 >= nrows) return;
    int r1 = min(r0 + rowsPerBlock, nrows);

    int cur = batch[r0];
    float local = 0.f;
    float cnt = 0.f;
    for (int i = r0; i < r1; ++i) {
        int g = batch[i];
        if (g != cur) {
            atomicAdd(&gsum[(size_t)cur * DIM + c], local);
            if (c == 0) atomicAdd(&gcnt[cur], cnt);
            local = 0.f; cnt = 0.f; cur = g;
        }
        local += xr[(size_t)i * DIM + c];
        cnt += 1.f;
    }
    atomicAdd(&gsum[(size_t)cur * DIM + c], local);
    if (c == 0) atomicAdd(&gcnt[cur], cnt);
}

__global__ __launch_bounds__(256) void finalize_kernel(
    const float* __restrict__ gsum, const float* __restrict__ gcnt,
    float* __restrict__ out)
{
    int idx = blockIdx.x * 256 + threadIdx.x;
    if (idx >= NGR * DIM) return;
    int g = idx >> 7;
    out[idx] = gsum[idx] / fmaxf(gcnt[g], 1.f);
}

// ---------------------------------------------------------------------------
extern "C" void kernel_launch(void* const* d_in, const int* in_sizes, int n_in,
                              void* d_out, int out_size, void* d_ws, size_t ws_size,
                              hipStream_t stream)
{
    const float* x_real    = (const float*)d_in[0];
    const float* x_virtual = (const float*)d_in[1];
    const float* W_root    = (const float*)d_in[2];
    const float* W_nbr     = (const float*)d_in[3];
    const float* bias      = (const float*)d_in[4];
    const int*   edge_rr   = (const int*)d_in[5];   // [2, E_RR]
    const int*   edge_rv   = (const int*)d_in[6];   // [2, N_R] row0=arange row1=vmap
    const int*   edge_vr   = (const int*)d_in[7];   // [2, N_R] row0=vmap  row1=arange
    const int*   batch     = (const int*)d_in[8];   // [N_R] sorted

    float* out = (float*)d_out;                     // [N_R*DIM] + [NGR*DIM]

    // ---- workspace layout ----
    float* ws   = (float*)d_ws;
    float* Arv  = ws;                               // N_V*DIM
    float* Tv   = Arv  + (size_t)N_V * DIM;
    float* xv_a = Tv   + (size_t)N_V * DIM;
    float* xv_b = xv_a + (size_t)N_V * DIM;
    float* bc   = xv_b + (size_t)N_V * DIM;         // NLAY*DIM
    float* gsum = bc   + (size_t)NLAY * DIM;        // NGR*DIM
    float* gcnt = gsum + (size_t)NGR * DIM;         // NGR
    ushort* xrb_in = (ushort*)(gcnt + NGR);         // N_R*DIM bf16
    ushort* xrb_a  = xrb_in + (size_t)N_R * DIM;
    ushort* xrb_b  = xrb_a  + (size_t)N_R * DIM;
    ushort* ArrB   = xrb_b  + (size_t)N_R * DIM;    // N_R*DIM bf16
    ushort* WT     = ArrB   + (size_t)N_R * DIM;    // NLAY*128*256 bf16
    int* iws       = (int*)(WT + (size_t)NLAY * DIM * 2 * DIM);
    int* cnt_r     = iws;                           // N_R
    int* rowptr_rr = cnt_r + N_R;                   // N_R+1
    int* cursor_rr = rowptr_rr + N_R + 1;           // N_R
    int* col_rr    = cursor_rr + N_R;               // E_RR
    int* cnt_v     = col_rr + E_RR;                 // N_V
    int* rowptr_rv = cnt_v + N_V;                   // N_V+1
    int* cursor_rv = rowptr_rv + N_V + 1;           // N_V
    int* col_rv    = cursor_rv + N_V;               // N_R

    const int* rr_src = edge_rr;
    const int* rr_dst = edge_rr + E_RR;
    const int* rv_src = edge_rv;
    const int* rv_dst = edge_rv + N_R;

    // CSR build (reused across layers)
    hipMemsetAsync(cnt_r, 0, (size_t)N_R * sizeof(int), stream);
    hipMemsetAsync(cnt_v, 0, (size_t)N_V * sizeof(int), stream);
    hist_kernel<<<(E_RR + 255) / 256, 256, 0, stream>>>(rr_dst, E_RR, cnt_r);
    hist_kernel<<<(N_R + 255) / 256, 256, 0, stream>>>(rv_dst, N_R, cnt_v);
    scan_kernel<<<1, 1024, 0, stream>>>(cnt_r, N_R, E_RR, rowptr_rr, cursor_rr);
    scan_kernel<<<1, 1024, 0, stream>>>(cnt_v, N_V, N_R, rowptr_rv, cursor_rv);
    fill_kernel<<<(E_RR + 255) / 256, 256, 0, stream>>>(rr_src, rr_dst, E_RR, cursor_rr, col_rr);
    fill_kernel<<<(N_R + 255) / 256, 256, 0, stream>>>(rv_src, rv_dst, N_R, cursor_rv, col_rv);

    // weights/bias prep + input conversion
    build_wt_kernel<<<(NLAY * DIM * 2 * DIM + 255) / 256, 256, 0, stream>>>(W_root, W_nbr, WT);
    combine_b_kernel<<<(NLAY * DIM + 255) / 256, 256, 0, stream>>>(bias, bc);
    conv_bf16_kernel<<<(N_R * DIM / 4 + 255) / 256, 256, 0, stream>>>(x_real, xrb_in, N_R * DIM / 4);

    const ushort* cur_xrb = xrb_in;
    const float*  cur_xv  = x_virtual;

    for (int l = 0; l < NLAY; ++l) {
        const float* Wn1 = W_nbr + ((size_t)l * 3 + 1) * DIM * DIM;  // r->v nbr
        const float* Wn2 = W_nbr + ((size_t)l * 3 + 2) * DIM * DIM;  // v->r nbr
        const float* Wr1 = W_root + ((size_t)l * 3 + 1) * DIM * DIM; // v root
        const float* b1  = bias + ((size_t)l * 3 + 1) * DIM;

        // A_rr[d] = sum x_r[src]  (bf16 gather, bf16 out)
        agg_kernel<<<(N_R * 64 + 255) / 256, 256, 0, stream>>>(
            rowptr_rr, col_rr, cur_xrb, ArrB, nullptr, N_R);

        // T_v = x_v @ Wn2 (fp32)
        gemm_kernel<<<(N_V + 7) / 8, 256, 0, stream>>>(
            cur_xv, Wn2, nullptr, nullptr, nullptr, Tv, N_V, 0);

        // x_r_new = relu( [x_r|A_rr] @ WT_l + Tv[vmap] + bc_l )
        ushort* xrb_out = (l == 0) ? xrb_a : ((l == 1) ? xrb_b : nullptr);
        float*  outF    = (l == NLAY - 1) ? out : nullptr;
        mfma_gemm_kernel<<<(N_R + 63) / 64, 256, 0, stream>>>(
            cur_xrb, ArrB, WT + (size_t)l * DIM * 2 * DIM,
            Tv, edge_vr, bc + (size_t)l * DIM, outF, xrb_out, N_R);

        if (l < NLAY - 1) {
            // A_rv[v] = sum x_r[r] over r with vmap[r]=v (fp32 out, uses layer input)
            agg_kernel<<<(N_V * 64 + 255) / 256, 256, 0, stream>>>(
                rowptr_rv, col_rv, cur_xrb, nullptr, Arv, N_V);
            // x_v_new = relu( x_v @ Wr1 + A_rv @ Wn1 + b1 )
            float* xv_out = (l & 1) ? xv_b : xv_a;
            gemm_kernel<<<(N_V + 7) / 8, 256, 0, stream>>>(
                cur_xv, Wr1, Arv, Wn1, b1, xv_out, N_V, 1);
            cur_xv = xv_out;
        }
        cur_xrb = xrb_out;
    }

    // readout: mean over real nodes per graph
    hipMemsetAsync(gsum, 0, (size_t)NGR * DIM * sizeof(float), stream);
    hipMemsetAsync(gcnt, 0, (size_t)NGR * sizeof(float), stream);
    const int rowsPerBlock = 256;
    readout_kernel<<<(N_R + rowsPerBlock - 1) / rowsPerBlock, 128, 0, stream>>>(
        out, batch, gsum, gcnt, N_R, rowsPerBlock);
    finalize_kernel<<<(NGR * DIM + 255) / 256, 256, 0, stream>>>(
        gsum, gcnt, out + (size_t)N_R * DIM);
}

// Round 4
// 594.103 us; speedup vs baseline: 8.6147x; 1.1711x over previous
//
#include <hip/hip_runtime.h>
#include <hip/hip_bf16.h>

// Problem constants (fixed by the reference setup_inputs()):
#define N_R   50000
#define N_V   2000
#define DIM   128
#define E_RR  800000
#define NLAY  3
#define NGR   32

typedef __attribute__((ext_vector_type(8))) short bf16x8;
typedef __attribute__((ext_vector_type(4))) float f32x4;

__device__ __forceinline__ ushort f2bf(float f) {
    unsigned u = __builtin_bit_cast(unsigned, f);
    unsigned r = (u + 0x7fffu + ((u >> 16) & 1u)) >> 16;   // RNE
    return (ushort)r;
}
__device__ __forceinline__ float bf2f(ushort h) {
    unsigned u = ((unsigned)h) << 16;
    return __builtin_bit_cast(float, u);
}

// ---------------------------------------------------------------------------
// CSR build: histogram -> 3-kernel device-wide scan -> fill
__global__ __launch_bounds__(256) void hist_kernel(
    const int* __restrict__ dst, int n, int* __restrict__ cnt)
{
    int i = blockIdx.x * 256 + threadIdx.x;
    if (i < n) atomicAdd(&cnt[dst[i]], 1);
}

// (1) per-block inclusive scan of cnt -> incl, plus per-block totals
__global__ __launch_bounds__(256) void scan1_kernel(
    const int* __restrict__ cnt, int n,
    int* __restrict__ incl, int* __restrict__ bsum)
{
    __shared__ int lds[256];
    int t = threadIdx.x;
    int i = blockIdx.x * 256 + t;
    int v = (i < n) ? cnt[i] : 0;
    lds[t] = v;
    __syncthreads();
    #pragma unroll
    for (int off = 1; off < 256; off <<= 1) {
        int u = (t >= off) ? lds[t - off] : 0;
        __syncthreads();
        lds[t] += u;
        __syncthreads();
    }
    if (i < n) incl[i] = lds[t];
    if (t == 255) bsum[blockIdx.x] = lds[255];
}

// (2) in-place EXCLUSIVE scan of block sums (nb <= 256)
__global__ __launch_bounds__(256) void scan2_kernel(
    int* __restrict__ bsum, int nb)
{
    __shared__ int lds[256];
    int t = threadIdx.x;
    int v = (t < nb) ? bsum[t] : 0;
    lds[t] = v;
    __syncthreads();
    #pragma unroll
    for (int off = 1; off < 256; off <<= 1) {
        int u = (t >= off) ? lds[t - off] : 0;
        __syncthreads();
        lds[t] += u;
        __syncthreads();
    }
    if (t < nb) bsum[t] = lds[t] - v;   // exclusive
}

// (3) rowptr/cursor = exclusive global scan
__global__ __launch_bounds__(256) void scan3_kernel(
    const int* __restrict__ cnt, const int* __restrict__ incl,
    const int* __restrict__ bsum, int n, int nedges,
    int* __restrict__ rowptr, int* __restrict__ cursor)
{
    int i = blockIdx.x * 256 + threadIdx.x;
    if (i < n) {
        int e = incl[i] - cnt[i] + bsum[blockIdx.x];
        rowptr[i] = e;
        cursor[i] = e;
    }
    if (i == 0) rowptr[n] = nedges;
}

__global__ __launch_bounds__(256) void fill_kernel(
    const int* __restrict__ src, const int* __restrict__ dst, int n,
    int* __restrict__ cursor, int* __restrict__ col)
{
    int i = blockIdx.x * 256 + threadIdx.x;
    if (i < n) {
        int p = atomicAdd(&cursor[dst[i]], 1);
        col[p] = src[i];
    }
}

// ---------------------------------------------------------------------------
// Convert fp32 matrix to bf16
__global__ __launch_bounds__(256) void conv_bf16_kernel(
    const float* __restrict__ in, ushort* __restrict__ out, int n4)
{
    int i = blockIdx.x * 256 + threadIdx.x;      // over n/4
    if (i >= n4) return;
    float4 v = *(const float4*)(in + (size_t)i * 4);
    ushort4 o;
    o.x = f2bf(v.x); o.y = f2bf(v.y); o.z = f2bf(v.z); o.w = f2bf(v.w);
    *(ushort4*)(out + (size_t)i * 4) = o;
}

// ---------------------------------------------------------------------------
// Build per-layer bf16 weight blocks, n-major:
//   WT[l][n][k] : k<128 -> Wroot[l,0,k,n]+Wroot[l,2,k,n] ; k>=128 -> Wnbr[l,0,k-128,n]
__global__ __launch_bounds__(256) void build_wt_kernel(
    const float* __restrict__ Wroot, const float* __restrict__ Wnbr,
    ushort* __restrict__ WT)
{
    int idx = blockIdx.x * 256 + threadIdx.x;    // over NLAY*128*256
    if (idx >= NLAY * DIM * 2 * DIM) return;
    int k = idx & 255;
    int n = (idx >> 8) & 127;
    int l = idx >> 15;
    float v;
    if (k < DIM) {
        const float* base = Wroot + (size_t)l * 3 * DIM * DIM;
        v = base[(size_t)k * DIM + n] + base[(size_t)(2 * DIM + k) * DIM + n];
    } else {
        v = Wnbr[((size_t)l * 3 * DIM + (k - DIM)) * DIM + n];
    }
    WT[idx] = f2bf(v);
}

__global__ __launch_bounds__(256) void combine_b_kernel(
    const float* __restrict__ bias, float* __restrict__ bc)
{
    int idx = blockIdx.x * 256 + threadIdx.x;           // over NLAY*DIM
    if (idx >= NLAY * DIM) return;
    int l = idx / DIM;
    int rest = idx - l * DIM;
    const float* base = bias + (size_t)l * 3 * DIM;
    bc[idx] = base[rest] + base[2 * DIM + rest];
}

// ---------------------------------------------------------------------------
// Gather-aggregate over bf16 features: out[d][:] = sum x[col[i]][:]
// One wave per destination row; lane owns 2 columns (one dword).
__global__ __launch_bounds__(256) void agg_kernel(
    const int* __restrict__ rowptr, const int* __restrict__ col,
    const ushort* __restrict__ x, ushort* __restrict__ outB,
    float* __restrict__ outF, int nrows)
{
    int gid = blockIdx.x * 256 + threadIdx.x;
    int w = gid >> 6;
    int lane = gid & 63;
    if (w >= nrows) return;
    int beg = rowptr[w], end = rowptr[w + 1];
    float ax = 0.f, ay = 0.f;
    int i = beg;
    for (; i + 1 < end; i += 2) {
        int s0 = col[i], s1 = col[i + 1];
        unsigned v0 = *(const unsigned*)(x + (size_t)s0 * DIM + lane * 2);
        unsigned v1 = *(const unsigned*)(x + (size_t)s1 * DIM + lane * 2);
        ax += bf2f((ushort)(v0 & 0xffff)) + bf2f((ushort)(v1 & 0xffff));
        ay += bf2f((ushort)(v0 >> 16))    + bf2f((ushort)(v1 >> 16));
    }
    if (i < end) {
        unsigned v0 = *(const unsigned*)(x + (size_t)col[i] * DIM + lane * 2);
        ax += bf2f((ushort)(v0 & 0xffff));
        ay += bf2f((ushort)(v0 >> 16));
    }
    if (outB) {
        unsigned o = (unsigned)f2bf(ax) | ((unsigned)f2bf(ay) << 16);
        *(unsigned*)(outB + (size_t)w * DIM + lane * 2) = o;
    }
    if (outF) {
        *(float2*)(outF + (size_t)w * DIM + lane * 2) = make_float2(ax, ay);
    }
}

// ---------------------------------------------------------------------------
// MFMA GEMM for the real-node update:
//   C[M][128] = relu( [A1|A2] @ W  + Tv[vmap[row]]  + bias ),  K = 256
// A1,A2: [M][128] bf16. WT: [128 n][256 k] bf16 (n-major).
// Block: 256 thr = 4 waves; 64 rows/block, wave handles 16 rows x 128 cols.
__global__ __launch_bounds__(256) void mfma_gemm_kernel(
    const ushort* __restrict__ A1, const ushort* __restrict__ A2,
    const ushort* __restrict__ WT, const float* __restrict__ Tv,
    const int* __restrict__ vmap, const float* __restrict__ bias,
    float* __restrict__ outF, ushort* __restrict__ outB, int M)
{
    int wave = threadIdx.x >> 6;
    int lane = threadIdx.x & 63;
    int rlo = lane & 15;          // A-row / B-col / C-col within tile
    int hi = lane >> 4;           // 0..3
    int row0 = blockIdx.x * 64 + wave * 16;
    int arow = row0 + rlo;
    int arowc = min(arow, M - 1);

    // preload 8 A-fragments: frag j covers k = 32j + 8*hi .. +7
    bf16x8 afr[8];
    #pragma unroll
    for (int j = 0; j < 8; ++j) {
        int k = 32 * j + 8 * hi;
        const ushort* src = (k < DIM)
            ? (A1 + (size_t)arowc * DIM + k)
            : (A2 + (size_t)arowc * DIM + (k - DIM));
        afr[j] = *(const bf16x8*)src;
    }

    f32x4 acc[8];
    #pragma unroll
    for (int n = 0; n < 8; ++n) acc[n] = (f32x4){0.f, 0.f, 0.f, 0.f};

    #pragma unroll
    for (int n = 0; n < 8; ++n) {
        const ushort* wrow = WT + (size_t)(n * 16 + rlo) * (2 * DIM);
        #pragma unroll
        for (int j = 0; j < 8; ++j) {
            bf16x8 bfr = *(const bf16x8*)(wrow + 32 * j + 8 * hi);
            acc[n] = __builtin_amdgcn_mfma_f32_16x16x32_bf16(afr[j], bfr, acc[n], 0, 0, 0);
        }
    }

    // epilogue: C row = row0 + 4*hi + i, col = n*16 + rlo
    const float* tvp[4];
    #pragma unroll
    for (int i = 0; i < 4; ++i) {
        int orow = row0 + 4 * hi + i;
        tvp[i] = (Tv != nullptr && orow < M)
                 ? (Tv + (size_t)vmap[orow] * DIM) : nullptr;
    }
    #pragma unroll
    for (int n = 0; n < 8; ++n) {
        int ncol = n * 16 + rlo;
        float bv = bias[ncol];
        #pragma unroll
        for (int i = 0; i < 4; ++i) {
            int orow = row0 + 4 * hi + i;
            if (orow >= M) continue;
            float v = acc[n][i] + bv;
            if (tvp[i]) v += tvp[i][ncol];
            v = fmaxf(v, 0.f);
            if (outF) outF[(size_t)orow * DIM + ncol] = v;
            if (outB) outB[(size_t)orow * DIM + ncol] = f2bf(v);
        }
    }
}

// ---------------------------------------------------------------------------
// Small fp32 GEMM (virtual-node paths, N_V rows):
//   out[i][:] = [relu]( A[i]@WA (+ B[i]@WB) (+ bias) )
__global__ __launch_bounds__(256) void gemm_kernel(
    const float* __restrict__ A,  const float* __restrict__ WA,
    const float* __restrict__ B,  const float* __restrict__ WB,
    const float* __restrict__ bias, float* __restrict__ out,
    int nrows, int doRelu)
{
    int t = threadIdx.x;
    int localRow = t >> 5;
    int j4 = (t & 31) << 2;
    int row = blockIdx.x * 8 + localRow;
    if (row >= nrows) return;

    float4 acc = make_float4(0.f, 0.f, 0.f, 0.f);
    const float* arow = A + (size_t)row * DIM;

    if (B != nullptr) {
        const float* brow = B + (size_t)row * DIM;
        #pragma unroll 8
        for (int k = 0; k < DIM; ++k) {
            float av = arow[k];
            float bv = brow[k];
            float4 wa = *(const float4*)(WA + (size_t)k * DIM + j4);
            float4 wb = *(const float4*)(WB + (size_t)k * DIM + j4);
            acc.x += av * wa.x + bv * wb.x;
            acc.y += av * wa.y + bv * wb.y;
            acc.z += av * wa.z + bv * wb.z;
            acc.w += av * wa.w + bv * wb.w;
        }
    } else {
        #pragma unroll 8
        for (int k = 0; k < DIM; ++k) {
            float av = arow[k];
            float4 wa = *(const float4*)(WA + (size_t)k * DIM + j4);
            acc.x += av * wa.x;
            acc.y += av * wa.y;
            acc.z += av * wa.z;
            acc.w += av * wa.w;
        }
    }
    if (bias != nullptr) {
        float4 b = *(const float4*)(bias + j4);
        acc.x += b.x; acc.y += b.y; acc.z += b.z; acc.w += b.w;
    }
    if (doRelu) {
        acc.x = fmaxf(acc.x, 0.f);
        acc.y = fmaxf(acc.y, 0.f);
        acc.z = fmaxf(acc.z, 0.f);
        acc.w = fmaxf(acc.w, 0.f);
    }
    *(float4*)(out + (size_t)row * DIM + j4) = acc;
}

// ---------------------------------------------------------------------------
// Readout: per-graph mean over real nodes (batch sorted; run-length + atomics)
__global__ __launch_bounds__(128) void readout_kernel(
    const float* __restrict__ xr, const int* __restrict__ batch,
    float* __restrict__ gsum, float* __restrict__ gcnt,
    int nrows, int rowsPerBlock)
{
    int c = threadIdx.x;
    int r0 = blockIdx.x * rowsPerBlock;
    if (r0 >= nrows) return;
    int r1 = min(r0 + rowsPerBlock, nrows);

    int cur = batch[r0];
    float local = 0.f;
    float cnt = 0.f;
    for (int i = r0; i < r1; ++i) {
        int g = batch[i];
        if (g != cur) {
            atomicAdd(&gsum[(size_t)cur * DIM + c], local);
            if (c == 0) atomicAdd(&gcnt[cur], cnt);
            local = 0.f; cnt = 0.f; cur = g;
        }
        local += xr[(size_t)i * DIM + c];
        cnt += 1.f;
    }
    atomicAdd(&gsum[(size_t)cur * DIM + c], local);
    if (c == 0) atomicAdd(&gcnt[cur], cnt);
}

__global__ __launch_bounds__(256) void finalize_kernel(
    const float* __restrict__ gsum, const float* __restrict__ gcnt,
    float* __restrict__ out)
{
    int idx = blockIdx.x * 256 + threadIdx.x;
    if (idx >= NGR * DIM) return;
    int g = idx >> 7;
    out[idx] = gsum[idx] / fmaxf(gcnt[g], 1.f);
}

// ---------------------------------------------------------------------------
extern "C" void kernel_launch(void* const* d_in, const int* in_sizes, int n_in,
                              void* d_out, int out_size, void* d_ws, size_t ws_size,
                              hipStream_t stream)
{
    const float* x_real    = (const float*)d_in[0];
    const float* x_virtual = (const float*)d_in[1];
    const float* W_root    = (const float*)d_in[2];
    const float* W_nbr     = (const float*)d_in[3];
    const float* bias      = (const float*)d_in[4];
    const int*   edge_rr   = (const int*)d_in[5];   // [2, E_RR]
    const int*   edge_rv   = (const int*)d_in[6];   // [2, N_R] row0=arange row1=vmap
    const int*   edge_vr   = (const int*)d_in[7];   // [2, N_R] row0=vmap  row1=arange
    const int*   batch     = (const int*)d_in[8];   // [N_R] sorted

    float* out = (float*)d_out;                     // [N_R*DIM] + [NGR*DIM]

    // ---- workspace layout ----
    float* ws   = (float*)d_ws;
    float* Arv  = ws;                               // N_V*DIM
    float* Tv   = Arv  + (size_t)N_V * DIM;
    float* xv_a = Tv   + (size_t)N_V * DIM;
    float* xv_b = xv_a + (size_t)N_V * DIM;
    float* bc   = xv_b + (size_t)N_V * DIM;         // NLAY*DIM
    float* gsum = bc   + (size_t)NLAY * DIM;        // NGR*DIM
    float* gcnt = gsum + (size_t)NGR * DIM;         // NGR
    ushort* xrb_in = (ushort*)(gcnt + NGR);         // N_R*DIM bf16
    ushort* xrb_a  = xrb_in + (size_t)N_R * DIM;
    ushort* xrb_b  = xrb_a  + (size_t)N_R * DIM;
    ushort* ArrB   = xrb_b  + (size_t)N_R * DIM;    // N_R*DIM bf16
    ushort* WT     = ArrB   + (size_t)N_R * DIM;    // NLAY*128*256 bf16
    int* iws       = (int*)(WT + (size_t)NLAY * DIM * 2 * DIM);
    int* cnt_r     = iws;                           // N_R
    int* rowptr_rr = cnt_r + N_R;                   // N_R+1
    int* cursor_rr = rowptr_rr + N_R + 1;           // N_R
    int* col_rr    = cursor_rr + N_R;               // E_RR
    int* cnt_v     = col_rr + E_RR;                 // N_V
    int* rowptr_rv = cnt_v + N_V;                   // N_V+1
    int* cursor_rv = rowptr_rv + N_V + 1;           // N_V
    int* col_rv    = cursor_rv + N_V;               // N_R
    int* incl      = col_rv + N_R;                  // N_R (scan temp)
    int* bsum      = incl + N_R;                    // 256 (scan temp)

    const int* rr_src = edge_rr;
    const int* rr_dst = edge_rr + E_RR;
    const int* rv_src = edge_rv;
    const int* rv_dst = edge_rv + N_R;

    const int nbR = (N_R + 255) / 256;
    const int nbV = (N_V + 255) / 256;

    // CSR build (reused across layers)
    hipMemsetAsync(cnt_r, 0, (size_t)N_R * sizeof(int), stream);
    hipMemsetAsync(cnt_v, 0, (size_t)N_V * sizeof(int), stream);
    hist_kernel<<<(E_RR + 255) / 256, 256, 0, stream>>>(rr_dst, E_RR, cnt_r);
    hist_kernel<<<(N_R + 255) / 256, 256, 0, stream>>>(rv_dst, N_R, cnt_v);

    scan1_kernel<<<nbR, 256, 0, stream>>>(cnt_r, N_R, incl, bsum);
    scan2_kernel<<<1, 256, 0, stream>>>(bsum, nbR);
    scan3_kernel<<<nbR, 256, 0, stream>>>(cnt_r, incl, bsum, N_R, E_RR,
                                          rowptr_rr, cursor_rr);
    scan1_kernel<<<nbV, 256, 0, stream>>>(cnt_v, N_V, incl, bsum);
    scan2_kernel<<<1, 256, 0, stream>>>(bsum, nbV);
    scan3_kernel<<<nbV, 256, 0, stream>>>(cnt_v, incl, bsum, N_V, N_R,
                                          rowptr_rv, cursor_rv);

    fill_kernel<<<(E_RR + 255) / 256, 256, 0, stream>>>(rr_src, rr_dst, E_RR, cursor_rr, col_rr);
    fill_kernel<<<(N_R + 255) / 256, 256, 0, stream>>>(rv_src, rv_dst, N_R, cursor_rv, col_rv);

    // weights/bias prep + input conversion
    build_wt_kernel<<<(NLAY * DIM * 2 * DIM + 255) / 256, 256, 0, stream>>>(W_root, W_nbr, WT);
    combine_b_kernel<<<(NLAY * DIM + 255) / 256, 256, 0, stream>>>(bias, bc);
    conv_bf16_kernel<<<(N_R * DIM / 4 + 255) / 256, 256, 0, stream>>>(x_real, xrb_in, N_R * DIM / 4);

    const ushort* cur_xrb = xrb_in;
    const float*  cur_xv  = x_virtual;

    for (int l = 0; l < NLAY; ++l) {
        const float* Wn1 = W_nbr + ((size_t)l * 3 + 1) * DIM * DIM;  // r->v nbr
        const float* Wn2 = W_nbr + ((size_t)l * 3 + 2) * DIM * DIM;  // v->r nbr
        const float* Wr1 = W_root + ((size_t)l * 3 + 1) * DIM * DIM; // v root
        const float* b1  = bias + ((size_t)l * 3 + 1) * DIM;

        // A_rr[d] = sum x_r[src]  (bf16 gather, bf16 out)
        agg_kernel<<<(N_R * 64 + 255) / 256, 256, 0, stream>>>(
            rowptr_rr, col_rr, cur_xrb, ArrB, nullptr, N_R);

        // T_v = x_v @ Wn2 (fp32)
        gemm_kernel<<<(N_V + 7) / 8, 256, 0, stream>>>(
            cur_xv, Wn2, nullptr, nullptr, nullptr, Tv, N_V, 0);

        // x_r_new = relu( [x_r|A_rr] @ WT_l + Tv[vmap] + bc_l )
        ushort* xrb_out = (l == 0) ? xrb_a : ((l == 1) ? xrb_b : nullptr);
        float*  outF    = (l == NLAY - 1) ? out : nullptr;
        mfma_gemm_kernel<<<(N_R + 63) / 64, 256, 0, stream>>>(
            cur_xrb, ArrB, WT + (size_t)l * DIM * 2 * DIM,
            Tv, edge_vr, bc + (size_t)l * DIM, outF, xrb_out, N_R);

        if (l < NLAY - 1) {
            // A_rv[v] = sum x_r[r] over r with vmap[r]=v (fp32 out, uses layer input)
            agg_kernel<<<(N_V * 64 + 255) / 256, 256, 0, stream>>>(
                rowptr_rv, col_rv, cur_xrb, nullptr, Arv, N_V);
            // x_v_new = relu( x_v @ Wr1 + A_rv @ Wn1 + b1 )
            float* xv_out = (l & 1) ? xv_b : xv_a;
            gemm_kernel<<<(N_V + 7) / 8, 256, 0, stream>>>(
                cur_xv, Wr1, Arv, Wn1, b1, xv_out, N_V, 1);
            cur_xv = xv_out;
        }
        cur_xrb = xrb_out;
    }

    // readout: mean over real nodes per graph
    hipMemsetAsync(gsum, 0, (size_t)NGR * DIM * sizeof(float), stream);
    hipMemsetAsync(gcnt, 0, (size_t)NGR * sizeof(float), stream);
    const int rowsPerBlock = 256;
    readout_kernel<<<(N_R + rowsPerBlock - 1) / rowsPerBlock, 128, 0, stream>>>(
        out, batch, gsum, gcnt, N_R, rowsPerBlock);
    finalize_kernel<<<(NGR * DIM + 255) / 256, 256, 0, stream>>>(
        gsum, gcnt, out + (size_t)N_R * DIM);
}

// Round 5
// 579.015 us; speedup vs baseline: 8.8392x; 1.0261x over previous
//
#include <hip/hip_runtime.h>
#include <hip/hip_bf16.h>

// Problem constants (fixed by the reference setup_inputs()):
#define N_R   50000
#define N_V   2000
#define DIM   128
#define E_RR  800000
#define NLAY  3
#define NGR   32

typedef __attribute__((ext_vector_type(8))) short bf16x8;
typedef __attribute__((ext_vector_type(4))) float f32x4;

__device__ __forceinline__ ushort f2bf(float f) {
    unsigned u = __builtin_bit_cast(unsigned, f);
    unsigned r = (u + 0x7fffu + ((u >> 16) & 1u)) >> 16;   // RNE
    return (ushort)r;
}
__device__ __forceinline__ float bf2f(ushort h) {
    unsigned u = ((unsigned)h) << 16;
    return __builtin_bit_cast(float, u);
}

// ---------------------------------------------------------------------------
// CSR build: histogram -> 3-kernel device-wide scan -> fill
__global__ __launch_bounds__(256) void hist_kernel(
    const int* __restrict__ dst, int n, int* __restrict__ cnt)
{
    int i = blockIdx.x * 256 + threadIdx.x;
    if (i < n) atomicAdd(&cnt[dst[i]], 1);
}

// (1) per-block inclusive scan of cnt -> incl, plus per-block totals
__global__ __launch_bounds__(256) void scan1_kernel(
    const int* __restrict__ cnt, int n,
    int* __restrict__ incl, int* __restrict__ bsum)
{
    __shared__ int lds[256];
    int t = threadIdx.x;
    int i = blockIdx.x * 256 + t;
    int v = (i < n) ? cnt[i] : 0;
    lds[t] = v;
    __syncthreads();
    #pragma unroll
    for (int off = 1; off < 256; off <<= 1) {
        int u = (t >= off) ? lds[t - off] : 0;
        __syncthreads();
        lds[t] += u;
        __syncthreads();
    }
    if (i < n) incl[i] = lds[t];
    if (t == 255) bsum[blockIdx.x] = lds[255];
}

// (2) in-place EXCLUSIVE scan of block sums (nb <= 256)
__global__ __launch_bounds__(256) void scan2_kernel(
    int* __restrict__ bsum, int nb)
{
    __shared__ int lds[256];
    int t = threadIdx.x;
    int v = (t < nb) ? bsum[t] : 0;
    lds[t] = v;
    __syncthreads();
    #pragma unroll
    for (int off = 1; off < 256; off <<= 1) {
        int u = (t >= off) ? lds[t - off] : 0;
        __syncthreads();
        lds[t] += u;
        __syncthreads();
    }
    if (t < nb) bsum[t] = lds[t] - v;   // exclusive
}

// (3) rowptr/cursor = exclusive global scan
__global__ __launch_bounds__(256) void scan3_kernel(
    const int* __restrict__ cnt, const int* __restrict__ incl,
    const int* __restrict__ bsum, int n, int nedges,
    int* __restrict__ rowptr, int* __restrict__ cursor)
{
    int i = blockIdx.x * 256 + threadIdx.x;
    if (i < n) {
        int e = incl[i] - cnt[i] + bsum[blockIdx.x];
        rowptr[i] = e;
        cursor[i] = e;
    }
    if (i == 0) rowptr[n] = nedges;
}

__global__ __launch_bounds__(256) void fill_kernel(
    const int* __restrict__ src, const int* __restrict__ dst, int n,
    int* __restrict__ cursor, int* __restrict__ col)
{
    int i = blockIdx.x * 256 + threadIdx.x;
    if (i < n) {
        int p = atomicAdd(&cursor[dst[i]], 1);
        col[p] = src[i];
    }
}

// ---------------------------------------------------------------------------
// Convert fp32 matrix to bf16
__global__ __launch_bounds__(256) void conv_bf16_kernel(
    const float* __restrict__ in, ushort* __restrict__ out, int n4)
{
    int i = blockIdx.x * 256 + threadIdx.x;      // over n/4
    if (i >= n4) return;
    float4 v = *(const float4*)(in + (size_t)i * 4);
    ushort4 o;
    o.x = f2bf(v.x); o.y = f2bf(v.y); o.z = f2bf(v.z); o.w = f2bf(v.w);
    *(ushort4*)(out + (size_t)i * 4) = o;
}

// ---------------------------------------------------------------------------
// Build per-layer bf16 weight blocks, n-major:
//   WT[l][n][k] : k<128 -> Wroot[l,0,k,n]+Wroot[l,2,k,n] ; k>=128 -> Wnbr[l,0,k-128,n]
__global__ __launch_bounds__(256) void build_wt_kernel(
    const float* __restrict__ Wroot, const float* __restrict__ Wnbr,
    ushort* __restrict__ WT)
{
    int idx = blockIdx.x * 256 + threadIdx.x;    // over NLAY*128*256
    if (idx >= NLAY * DIM * 2 * DIM) return;
    int k = idx & 255;
    int n = (idx >> 8) & 127;
    int l = idx >> 15;
    float v;
    if (k < DIM) {
        const float* base = Wroot + (size_t)l * 3 * DIM * DIM;
        v = base[(size_t)k * DIM + n] + base[(size_t)(2 * DIM + k) * DIM + n];
    } else {
        v = Wnbr[((size_t)l * 3 * DIM + (k - DIM)) * DIM + n];
    }
    WT[idx] = f2bf(v);
}

__global__ __launch_bounds__(256) void combine_b_kernel(
    const float* __restrict__ bias, float* __restrict__ bc)
{
    int idx = blockIdx.x * 256 + threadIdx.x;           // over NLAY*DIM
    if (idx >= NLAY * DIM) return;
    int l = idx / DIM;
    int rest = idx - l * DIM;
    const float* base = bias + (size_t)l * 3 * DIM;
    bc[idx] = base[rest] + base[2 * DIM + rest];
}

// ---------------------------------------------------------------------------
// Gather-aggregate over bf16 features: out[d][:] = sum x[col[i]][:]
// One wave per destination row; lane owns 2 columns (one dword).
__global__ __launch_bounds__(256) void agg_kernel(
    const int* __restrict__ rowptr, const int* __restrict__ col,
    const ushort* __restrict__ x, ushort* __restrict__ outB,
    float* __restrict__ outF, int nrows)
{
    int gid = blockIdx.x * 256 + threadIdx.x;
    int w = gid >> 6;
    int lane = gid & 63;
    if (w >= nrows) return;
    int beg = rowptr[w], end = rowptr[w + 1];
    float ax = 0.f, ay = 0.f;
    int i = beg;
    for (; i + 1 < end; i += 2) {
        int s0 = col[i], s1 = col[i + 1];
        unsigned v0 = *(const unsigned*)(x + (size_t)s0 * DIM + lane * 2);
        unsigned v1 = *(const unsigned*)(x + (size_t)s1 * DIM + lane * 2);
        ax += bf2f((ushort)(v0 & 0xffff)) + bf2f((ushort)(v1 & 0xffff));
        ay += bf2f((ushort)(v0 >> 16))    + bf2f((ushort)(v1 >> 16));
    }
    if (i < end) {
        unsigned v0 = *(const unsigned*)(x + (size_t)col[i] * DIM + lane * 2);
        ax += bf2f((ushort)(v0 & 0xffff));
        ay += bf2f((ushort)(v0 >> 16));
    }
    if (outB) {
        unsigned o = (unsigned)f2bf(ax) | ((unsigned)f2bf(ay) << 16);
        *(unsigned*)(outB + (size_t)w * DIM + lane * 2) = o;
    }
    if (outF) {
        *(float2*)(outF + (size_t)w * DIM + lane * 2) = make_float2(ax, ay);
    }
}

// ---------------------------------------------------------------------------
// MFMA GEMM for the real-node update:
//   C[M][128] = relu( [A1|A2] @ W  + Tv[vmap[row]]  + bias ),  K = 256
__global__ __launch_bounds__(256) void mfma_gemm_kernel(
    const ushort* __restrict__ A1, const ushort* __restrict__ A2,
    const ushort* __restrict__ WT, const float* __restrict__ Tv,
    const int* __restrict__ vmap, const float* __restrict__ bias,
    float* __restrict__ outF, ushort* __restrict__ outB, int M)
{
    int wave = threadIdx.x >> 6;
    int lane = threadIdx.x & 63;
    int rlo = lane & 15;          // A-row / B-col / C-col within tile
    int hi = lane >> 4;           // 0..3
    int row0 = blockIdx.x * 64 + wave * 16;
    int arow = row0 + rlo;
    int arowc = min(arow, M - 1);

    // preload 8 A-fragments: frag j covers k = 32j + 8*hi .. +7
    bf16x8 afr[8];
    #pragma unroll
    for (int j = 0; j < 8; ++j) {
        int k = 32 * j + 8 * hi;
        const ushort* src = (k < DIM)
            ? (A1 + (size_t)arowc * DIM + k)
            : (A2 + (size_t)arowc * DIM + (k - DIM));
        afr[j] = *(const bf16x8*)src;
    }

    f32x4 acc[8];
    #pragma unroll
    for (int n = 0; n < 8; ++n) acc[n] = (f32x4){0.f, 0.f, 0.f, 0.f};

    #pragma unroll
    for (int n = 0; n < 8; ++n) {
        const ushort* wrow = WT + (size_t)(n * 16 + rlo) * (2 * DIM);
        #pragma unroll
        for (int j = 0; j < 8; ++j) {
            bf16x8 bfr = *(const bf16x8*)(wrow + 32 * j + 8 * hi);
            acc[n] = __builtin_amdgcn_mfma_f32_16x16x32_bf16(afr[j], bfr, acc[n], 0, 0, 0);
        }
    }

    // epilogue: C row = row0 + 4*hi + i, col = n*16 + rlo
    const float* tvp[4];
    #pragma unroll
    for (int i = 0; i < 4; ++i) {
        int orow = row0 + 4 * hi + i;
        tvp[i] = (Tv != nullptr && orow < M)
                 ? (Tv + (size_t)vmap[orow] * DIM) : nullptr;
    }
    #pragma unroll
    for (int n = 0; n < 8; ++n) {
        int ncol = n * 16 + rlo;
        float bv = bias[ncol];
        #pragma unroll
        for (int i = 0; i < 4; ++i) {
            int orow = row0 + 4 * hi + i;
            if (orow >= M) continue;
            float v = acc[n][i] + bv;
            if (tvp[i]) v += tvp[i][ncol];
            v = fmaxf(v, 0.f);
            if (outF) outF[(size_t)orow * DIM + ncol] = v;
            if (outB) outB[(size_t)orow * DIM + ncol] = f2bf(v);
        }
    }
}

// ---------------------------------------------------------------------------
// Small fp32 GEMM (virtual-node paths, N_V rows):
//   out[i][:] = [relu]( A[i]@WA (+ B[i]@WB) (+ bias) )
__global__ __launch_bounds__(256) void gemm_kernel(
    const float* __restrict__ A,  const float* __restrict__ WA,
    const float* __restrict__ B,  const float* __restrict__ WB,
    const float* __restrict__ bias, float* __restrict__ out,
    int nrows, int doRelu)
{
    int t = threadIdx.x;
    int localRow = t >> 5;
    int j4 = (t & 31) << 2;
    int row = blockIdx.x * 8 + localRow;
    if (row >= nrows) return;

    float4 acc = make_float4(0.f, 0.f, 0.f, 0.f);
    const float* arow = A + (size_t)row * DIM;

    if (B != nullptr) {
        const float* brow = B + (size_t)row * DIM;
        #pragma unroll 8
        for (int k = 0; k < DIM; ++k) {
            float av = arow[k];
            float bv = brow[k];
            float4 wa = *(const float4*)(WA + (size_t)k * DIM + j4);
            float4 wb = *(const float4*)(WB + (size_t)k * DIM + j4);
            acc.x += av * wa.x + bv * wb.x;
            acc.y += av * wa.y + bv * wb.y;
            acc.z += av * wa.z + bv * wb.z;
            acc.w += av * wa.w + bv * wb.w;
        }
    } else {
        #pragma unroll 8
        for (int k = 0; k < DIM; ++k) {
            float av = arow[k];
            float4 wa = *(const float4*)(WA + (size_t)k * DIM + j4);
            acc.x += av * wa.x;
            acc.y += av * wa.y;
            acc.z += av * wa.z;
            acc.w += av * wa.w;
        }
    }
    if (bias != nullptr) {
        float4 b = *(const float4*)(bias + j4);
        acc.x += b.x; acc.y += b.y; acc.z += b.z; acc.w += b.w;
    }
    if (doRelu) {
        acc.x = fmaxf(acc.x, 0.f);
        acc.y = fmaxf(acc.y, 0.f);
        acc.z = fmaxf(acc.z, 0.f);
        acc.w = fmaxf(acc.w, 0.f);
    }
    *(float4*)(out + (size_t)row * DIM + j4) = acc;
}

// ---------------------------------------------------------------------------
// Readout: per-graph mean over real nodes.
// 64 rows/block, 256 threads: thread owns cols 4*(t&31).. and rows r0+(t>>5)+8i.
// batch sorted -> per-thread run-length accumulate, flush on boundary.
__global__ __launch_bounds__(256) void readout_kernel(
    const float* __restrict__ xr, const int* __restrict__ batch,
    float* __restrict__ gsum, float* __restrict__ gcnt, int nrows)
{
    int t = threadIdx.x;
    int c4 = (t & 31) << 2;
    int rsub = t >> 5;                 // 0..7
    int r0 = blockIdx.x * 64;
    int r = r0 + rsub;
    if (r >= nrows) return;

    int cur = batch[r];
    float4 acc = make_float4(0.f, 0.f, 0.f, 0.f);
    float cnt = 0.f;
    for (; r < min(r0 + 64, nrows); r += 8) {
        int g = batch[r];
        if (g != cur) {
            atomicAdd(&gsum[(size_t)cur * DIM + c4 + 0], acc.x);
            atomicAdd(&gsum[(size_t)cur * DIM + c4 + 1], acc.y);
            atomicAdd(&gsum[(size_t)cur * DIM + c4 + 2], acc.z);
            atomicAdd(&gsum[(size_t)cur * DIM + c4 + 3], acc.w);
            if (c4 == 0) atomicAdd(&gcnt[cur], cnt);
            acc = make_float4(0.f, 0.f, 0.f, 0.f);
            cnt = 0.f;
            cur = g;
        }
        float4 v = *(const float4*)(xr + (size_t)r * DIM + c4);
        acc.x += v.x; acc.y += v.y; acc.z += v.z; acc.w += v.w;
        cnt += 1.f;
    }
    atomicAdd(&gsum[(size_t)cur * DIM + c4 + 0], acc.x);
    atomicAdd(&gsum[(size_t)cur * DIM + c4 + 1], acc.y);
    atomicAdd(&gsum[(size_t)cur * DIM + c4 + 2], acc.z);
    atomicAdd(&gsum[(size_t)cur * DIM + c4 + 3], acc.w);
    if (c4 == 0) atomicAdd(&gcnt[cur], cnt);
}

__global__ __launch_bounds__(256) void finalize_kernel(
    const float* __restrict__ gsum, const float* __restrict__ gcnt,
    float* __restrict__ out)
{
    int idx = blockIdx.x * 256 + threadIdx.x;
    if (idx >= NGR * DIM) return;
    int g = idx >> 7;
    out[idx] = gsum[idx] / fmaxf(gcnt[g], 1.f);
}

// ---------------------------------------------------------------------------
extern "C" void kernel_launch(void* const* d_in, const int* in_sizes, int n_in,
                              void* d_out, int out_size, void* d_ws, size_t ws_size,
                              hipStream_t stream)
{
    const float* x_real    = (const float*)d_in[0];
    const float* x_virtual = (const float*)d_in[1];
    const float* W_root    = (const float*)d_in[2];
    const float* W_nbr     = (const float*)d_in[3];
    const float* bias      = (const float*)d_in[4];
    const int*   edge_rr   = (const int*)d_in[5];   // [2, E_RR]
    const int*   edge_rv   = (const int*)d_in[6];   // [2, N_R] row0=arange row1=vmap
    const int*   edge_vr   = (const int*)d_in[7];   // [2, N_R] row0=vmap  row1=arange
    const int*   batch     = (const int*)d_in[8];   // [N_R] sorted

    float* out = (float*)d_out;                     // [N_R*DIM] + [NGR*DIM]

    // ---- workspace layout ----
    float* ws   = (float*)d_ws;
    float* Arv  = ws;                               // N_V*DIM
    float* Tv   = Arv  + (size_t)N_V * DIM;
    float* xv_a = Tv   + (size_t)N_V * DIM;
    float* xv_b = xv_a + (size_t)N_V * DIM;
    float* bc   = xv_b + (size_t)N_V * DIM;         // NLAY*DIM
    float* gsum = bc   + (size_t)NLAY * DIM;        // NGR*DIM
    float* gcnt = gsum + (size_t)NGR * DIM;         // NGR
    ushort* xrb_in = (ushort*)(gcnt + NGR);         // N_R*DIM bf16
    ushort* xrb_a  = xrb_in + (size_t)N_R * DIM;
    ushort* xrb_b  = xrb_a  + (size_t)N_R * DIM;
    ushort* ArrB   = xrb_b  + (size_t)N_R * DIM;    // N_R*DIM bf16
    ushort* WT     = ArrB   + (size_t)N_R * DIM;    // NLAY*128*256 bf16
    int* iws       = (int*)(WT + (size_t)NLAY * DIM * 2 * DIM);
    int* cnt_r     = iws;                           // N_R
    int* rowptr_rr = cnt_r + N_R;                   // N_R+1
    int* cursor_rr = rowptr_rr + N_R + 1;           // N_R
    int* col_rr    = cursor_rr + N_R;               // E_RR
    int* cnt_v     = col_rr + E_RR;                 // N_V
    int* rowptr_rv = cnt_v + N_V;                   // N_V+1
    int* cursor_rv = rowptr_rv + N_V + 1;           // N_V
    int* col_rv    = cursor_rv + N_V;               // N_R
    int* incl      = col_rv + N_R;                  // N_R (scan temp)
    int* bsum      = incl + N_R;                    // 256 (scan temp)

    const int* rr_src = edge_rr;
    const int* rr_dst = edge_rr + E_RR;
    const int* rv_src = edge_rv;
    const int* rv_dst = edge_rv + N_R;

    const int nbR = (N_R + 255) / 256;
    const int nbV = (N_V + 255) / 256;

    // CSR build (reused across layers)
    hipMemsetAsync(cnt_r, 0, (size_t)N_R * sizeof(int), stream);
    hipMemsetAsync(cnt_v, 0, (size_t)N_V * sizeof(int), stream);
    hist_kernel<<<(E_RR + 255) / 256, 256, 0, stream>>>(rr_dst, E_RR, cnt_r);
    hist_kernel<<<(N_R + 255) / 256, 256, 0, stream>>>(rv_dst, N_R, cnt_v);

    scan1_kernel<<<nbR, 256, 0, stream>>>(cnt_r, N_R, incl, bsum);
    scan2_kernel<<<1, 256, 0, stream>>>(bsum, nbR);
    scan3_kernel<<<nbR, 256, 0, stream>>>(cnt_r, incl, bsum, N_R, E_RR,
                                          rowptr_rr, cursor_rr);
    scan1_kernel<<<nbV, 256, 0, stream>>>(cnt_v, N_V, incl, bsum);
    scan2_kernel<<<1, 256, 0, stream>>>(bsum, nbV);
    scan3_kernel<<<nbV, 256, 0, stream>>>(cnt_v, incl, bsum, N_V, N_R,
                                          rowptr_rv, cursor_rv);

    fill_kernel<<<(E_RR + 255) / 256, 256, 0, stream>>>(rr_src, rr_dst, E_RR, cursor_rr, col_rr);
    fill_kernel<<<(N_R + 255) / 256, 256, 0, stream>>>(rv_src, rv_dst, N_R, cursor_rv, col_rv);

    // weights/bias prep + input conversion
    build_wt_kernel<<<(NLAY * DIM * 2 * DIM + 255) / 256, 256, 0, stream>>>(W_root, W_nbr, WT);
    combine_b_kernel<<<(NLAY * DIM + 255) / 256, 256, 0, stream>>>(bias, bc);
    conv_bf16_kernel<<<(N_R * DIM / 4 + 255) / 256, 256, 0, stream>>>(x_real, xrb_in, N_R * DIM / 4);

    const ushort* cur_xrb = xrb_in;
    const float*  cur_xv  = x_virtual;

    for (int l = 0; l < NLAY; ++l) {
        const float* Wn1 = W_nbr + ((size_t)l * 3 + 1) * DIM * DIM;  // r->v nbr
        const float* Wn2 = W_nbr + ((size_t)l * 3 + 2) * DIM * DIM;  // v->r nbr
        const float* Wr1 = W_root + ((size_t)l * 3 + 1) * DIM * DIM; // v root
        const float* b1  = bias + ((size_t)l * 3 + 1) * DIM;

        // A_rr[d] = sum x_r[src]  (bf16 gather, bf16 out)
        agg_kernel<<<(N_R * 64 + 255) / 256, 256, 0, stream>>>(
            rowptr_rr, col_rr, cur_xrb, ArrB, nullptr, N_R);

        // T_v = x_v @ Wn2 (fp32)
        gemm_kernel<<<(N_V + 7) / 8, 256, 0, stream>>>(
            cur_xv, Wn2, nullptr, nullptr, nullptr, Tv, N_V, 0);

        // x_r_new = relu( [x_r|A_rr] @ WT_l + Tv[vmap] + bc_l )
        ushort* xrb_out = (l == 0) ? xrb_a : ((l == 1) ? xrb_b : nullptr);
        float*  outF    = (l == NLAY - 1) ? out : nullptr;
        mfma_gemm_kernel<<<(N_R + 63) / 64, 256, 0, stream>>>(
            cur_xrb, ArrB, WT + (size_t)l * DIM * 2 * DIM,
            Tv, edge_vr, bc + (size_t)l * DIM, outF, xrb_out, N_R);

        if (l < NLAY - 1) {
            // A_rv[v] = sum x_r[r] over r with vmap[r]=v (fp32 out, uses layer input)
            agg_kernel<<<(N_V * 64 + 255) / 256, 256, 0, stream>>>(
                rowptr_rv, col_rv, cur_xrb, nullptr, Arv, N_V);
            // x_v_new = relu( x_v @ Wr1 + A_rv @ Wn1 + b1 )
            float* xv_out = (l & 1) ? xv_b : xv_a;
            gemm_kernel<<<(N_V + 7) / 8, 256, 0, stream>>>(
                cur_xv, Wr1, Arv, Wn1, b1, xv_out, N_V, 1);
            cur_xv = xv_out;
        }
        cur_xrb = xrb_out;
    }

    // readout: mean over real nodes per graph
    hipMemsetAsync(gsum, 0, (size_t)NGR * DIM * sizeof(float), stream);
    hipMemsetAsync(gcnt, 0, (size_t)NGR * sizeof(float), stream);
    readout_kernel<<<(N_R + 63) / 64, 256, 0, stream>>>(
        out, batch, gsum, gcnt, N_R);
    finalize_kernel<<<(NGR * DIM + 255) / 256, 256, 0, stream>>>(
        gsum, gcnt, out + (size_t)N_R * DIM);
}

// Round 6
// 543.822 us; speedup vs baseline: 9.4112x; 1.0647x over previous
//
#include <hip/hip_runtime.h>
#include <hip/hip_bf16.h>

// Problem constants (fixed by the reference setup_inputs()):
#define N_R   50000
#define N_V   2000
#define DIM   128
#define E_RR  800000
#define NLAY  3
#define NGR   32
#define RCHUNK 16   // readout chunks per graph

typedef __attribute__((ext_vector_type(8))) short bf16x8;
typedef __attribute__((ext_vector_type(4))) float f32x4;

__device__ __forceinline__ ushort f2bf(float f) {
    unsigned u = __builtin_bit_cast(unsigned, f);
    unsigned r = (u + 0x7fffu + ((u >> 16) & 1u)) >> 16;   // RNE
    return (ushort)r;
}
__device__ __forceinline__ float bf2f(ushort h) {
    unsigned u = ((unsigned)h) << 16;
    return __builtin_bit_cast(float, u);
}
__device__ __forceinline__ int lbound(const int* __restrict__ a, int n, int key) {
    int lo = 0, hi = n;
    while (lo < hi) { int mid = (lo + hi) >> 1; if (a[mid] < key) lo = mid + 1; else hi = mid; }
    return lo;
}

// ---------------------------------------------------------------------------
// CSR build: histogram -> 3-kernel device-wide scan -> fill
__global__ __launch_bounds__(256) void hist_kernel(
    const int* __restrict__ dst, int n, int* __restrict__ cnt)
{
    int i = blockIdx.x * 256 + threadIdx.x;
    if (i < n) atomicAdd(&cnt[dst[i]], 1);
}

// (1) per-block inclusive scan of cnt -> incl, plus per-block totals
__global__ __launch_bounds__(256) void scan1_kernel(
    const int* __restrict__ cnt, int n,
    int* __restrict__ incl, int* __restrict__ bsum)
{
    __shared__ int lds[256];
    int t = threadIdx.x;
    int i = blockIdx.x * 256 + t;
    int v = (i < n) ? cnt[i] : 0;
    lds[t] = v;
    __syncthreads();
    #pragma unroll
    for (int off = 1; off < 256; off <<= 1) {
        int u = (t >= off) ? lds[t - off] : 0;
        __syncthreads();
        lds[t] += u;
        __syncthreads();
    }
    if (i < n) incl[i] = lds[t];
    if (t == 255) bsum[blockIdx.x] = lds[255];
}

// (2) in-place EXCLUSIVE scan of block sums (nb <= 256)
__global__ __launch_bounds__(256) void scan2_kernel(
    int* __restrict__ bsum, int nb)
{
    __shared__ int lds[256];
    int t = threadIdx.x;
    int v = (t < nb) ? bsum[t] : 0;
    lds[t] = v;
    __syncthreads();
    #pragma unroll
    for (int off = 1; off < 256; off <<= 1) {
        int u = (t >= off) ? lds[t - off] : 0;
        __syncthreads();
        lds[t] += u;
        __syncthreads();
    }
    if (t < nb) bsum[t] = lds[t] - v;   // exclusive
}

// (3) rowptr/cursor = exclusive global scan
__global__ __launch_bounds__(256) void scan3_kernel(
    const int* __restrict__ cnt, const int* __restrict__ incl,
    const int* __restrict__ bsum, int n, int nedges,
    int* __restrict__ rowptr, int* __restrict__ cursor)
{
    int i = blockIdx.x * 256 + threadIdx.x;
    if (i < n) {
        int e = incl[i] - cnt[i] + bsum[blockIdx.x];
        rowptr[i] = e;
        cursor[i] = e;
    }
    if (i == 0) rowptr[n] = nedges;
}

__global__ __launch_bounds__(256) void fill_kernel(
    const int* __restrict__ src, const int* __restrict__ dst, int n,
    int* __restrict__ cursor, int* __restrict__ col)
{
    int i = blockIdx.x * 256 + threadIdx.x;
    if (i < n) {
        int p = atomicAdd(&cursor[dst[i]], 1);
        col[p] = src[i];
    }
}

// ---------------------------------------------------------------------------
// Convert fp32 matrix to bf16
__global__ __launch_bounds__(256) void conv_bf16_kernel(
    const float* __restrict__ in, ushort* __restrict__ out, int n4)
{
    int i = blockIdx.x * 256 + threadIdx.x;      // over n/4
    if (i >= n4) return;
    float4 v = *(const float4*)(in + (size_t)i * 4);
    ushort4 o;
    o.x = f2bf(v.x); o.y = f2bf(v.y); o.z = f2bf(v.z); o.w = f2bf(v.w);
    *(ushort4*)(out + (size_t)i * 4) = o;
}

// ---------------------------------------------------------------------------
// Build per-layer bf16 weight blocks, n-major:
//   WT[l][n][k] : k<128 -> Wroot[l,0,k,n]+Wroot[l,2,k,n] ; k>=128 -> Wnbr[l,0,k-128,n]
__global__ __launch_bounds__(256) void build_wt_kernel(
    const float* __restrict__ Wroot, const float* __restrict__ Wnbr,
    ushort* __restrict__ WT)
{
    int idx = blockIdx.x * 256 + threadIdx.x;    // over NLAY*128*256
    if (idx >= NLAY * DIM * 2 * DIM) return;
    int k = idx & 255;
    int n = (idx >> 8) & 127;
    int l = idx >> 15;
    float v;
    if (k < DIM) {
        const float* base = Wroot + (size_t)l * 3 * DIM * DIM;
        v = base[(size_t)k * DIM + n] + base[(size_t)(2 * DIM + k) * DIM + n];
    } else {
        v = Wnbr[((size_t)l * 3 * DIM + (k - DIM)) * DIM + n];
    }
    WT[idx] = f2bf(v);
}

__global__ __launch_bounds__(256) void combine_b_kernel(
    const float* __restrict__ bias, float* __restrict__ bc)
{
    int idx = blockIdx.x * 256 + threadIdx.x;           // over NLAY*DIM
    if (idx >= NLAY * DIM) return;
    int l = idx / DIM;
    int rest = idx - l * DIM;
    const float* base = bias + (size_t)l * 3 * DIM;
    bc[idx] = base[rest] + base[2 * DIM + rest];
}

// ---------------------------------------------------------------------------
// Gather-aggregate over bf16 features: out[d][:] = sum x[col[i]][:]
// One wave per destination row; lane owns 2 columns (one dword).
__global__ __launch_bounds__(256) void agg_kernel(
    const int* __restrict__ rowptr, const int* __restrict__ col,
    const ushort* __restrict__ x, ushort* __restrict__ outB,
    float* __restrict__ outF, int nrows)
{
    int gid = blockIdx.x * 256 + threadIdx.x;
    int w = gid >> 6;
    int lane = gid & 63;
    if (w >= nrows) return;
    int beg = rowptr[w], end = rowptr[w + 1];
    float ax = 0.f, ay = 0.f;
    int i = beg;
    for (; i + 1 < end; i += 2) {
        int s0 = col[i], s1 = col[i + 1];
        unsigned v0 = *(const unsigned*)(x + (size_t)s0 * DIM + lane * 2);
        unsigned v1 = *(const unsigned*)(x + (size_t)s1 * DIM + lane * 2);
        ax += bf2f((ushort)(v0 & 0xffff)) + bf2f((ushort)(v1 & 0xffff));
        ay += bf2f((ushort)(v0 >> 16))    + bf2f((ushort)(v1 >> 16));
    }
    if (i < end) {
        unsigned v0 = *(const unsigned*)(x + (size_t)col[i] * DIM + lane * 2);
        ax += bf2f((ushort)(v0 & 0xffff));
        ay += bf2f((ushort)(v0 >> 16));
    }
    if (outB) {
        unsigned o = (unsigned)f2bf(ax) | ((unsigned)f2bf(ay) << 16);
        *(unsigned*)(outB + (size_t)w * DIM + lane * 2) = o;
    }
    if (outF) {
        *(float2*)(outF + (size_t)w * DIM + lane * 2) = make_float2(ax, ay);
    }
}

// ---------------------------------------------------------------------------
// MFMA GEMM for the real-node update:
//   C[M][128] = relu( [A1|A2] @ W  + Tv[vmap[row]]  + bias ),  K = 256
__global__ __launch_bounds__(256) void mfma_gemm_kernel(
    const ushort* __restrict__ A1, const ushort* __restrict__ A2,
    const ushort* __restrict__ WT, const float* __restrict__ Tv,
    const int* __restrict__ vmap, const float* __restrict__ bias,
    float* __restrict__ outF, ushort* __restrict__ outB, int M)
{
    int wave = threadIdx.x >> 6;
    int lane = threadIdx.x & 63;
    int rlo = lane & 15;          // A-row / B-col / C-col within tile
    int hi = lane >> 4;           // 0..3
    int row0 = blockIdx.x * 64 + wave * 16;
    int arow = row0 + rlo;
    int arowc = min(arow, M - 1);

    // preload 8 A-fragments: frag j covers k = 32j + 8*hi .. +7
    bf16x8 afr[8];
    #pragma unroll
    for (int j = 0; j < 8; ++j) {
        int k = 32 * j + 8 * hi;
        const ushort* src = (k < DIM)
            ? (A1 + (size_t)arowc * DIM + k)
            : (A2 + (size_t)arowc * DIM + (k - DIM));
        afr[j] = *(const bf16x8*)src;
    }

    f32x4 acc[8];
    #pragma unroll
    for (int n = 0; n < 8; ++n) acc[n] = (f32x4){0.f, 0.f, 0.f, 0.f};

    #pragma unroll
    for (int n = 0; n < 8; ++n) {
        const ushort* wrow = WT + (size_t)(n * 16 + rlo) * (2 * DIM);
        #pragma unroll
        for (int j = 0; j < 8; ++j) {
            bf16x8 bfr = *(const bf16x8*)(wrow + 32 * j + 8 * hi);
            acc[n] = __builtin_amdgcn_mfma_f32_16x16x32_bf16(afr[j], bfr, acc[n], 0, 0, 0);
        }
    }

    // epilogue: C row = row0 + 4*hi + i, col = n*16 + rlo
    const float* tvp[4];
    #pragma unroll
    for (int i = 0; i < 4; ++i) {
        int orow = row0 + 4 * hi + i;
        tvp[i] = (Tv != nullptr && orow < M)
                 ? (Tv + (size_t)vmap[orow] * DIM) : nullptr;
    }
    #pragma unroll
    for (int n = 0; n < 8; ++n) {
        int ncol = n * 16 + rlo;
        float bv = bias[ncol];
        #pragma unroll
        for (int i = 0; i < 4; ++i) {
            int orow = row0 + 4 * hi + i;
            if (orow >= M) continue;
            float v = acc[n][i] + bv;
            if (tvp[i]) v += tvp[i][ncol];
            v = fmaxf(v, 0.f);
            if (outF) outF[(size_t)orow * DIM + ncol] = v;
            if (outB) outB[(size_t)orow * DIM + ncol] = f2bf(v);
        }
    }
}

// ---------------------------------------------------------------------------
// Small fp32 GEMM (virtual-node paths, N_V rows):
//   out[i][:] = [relu]( A[i]@WA (+ B[i]@WB) (+ bias) )
__global__ __launch_bounds__(256) void gemm_kernel(
    const float* __restrict__ A,  const float* __restrict__ WA,
    const float* __restrict__ B,  const float* __restrict__ WB,
    const float* __restrict__ bias, float* __restrict__ out,
    int nrows, int doRelu)
{
    int t = threadIdx.x;
    int localRow = t >> 5;
    int j4 = (t & 31) << 2;
    int row = blockIdx.x * 8 + localRow;
    if (row >= nrows) return;

    float4 acc = make_float4(0.f, 0.f, 0.f, 0.f);
    const float* arow = A + (size_t)row * DIM;

    if (B != nullptr) {
        const float* brow = B + (size_t)row * DIM;
        #pragma unroll 8
        for (int k = 0; k < DIM; ++k) {
            float av = arow[k];
            float bv = brow[k];
            float4 wa = *(const float4*)(WA + (size_t)k * DIM + j4);
            float4 wb = *(const float4*)(WB + (size_t)k * DIM + j4);
            acc.x += av * wa.x + bv * wb.x;
            acc.y += av * wa.y + bv * wb.y;
            acc.z += av * wa.z + bv * wb.z;
            acc.w += av * wa.w + bv * wb.w;
        }
    } else {
        #pragma unroll 8
        for (int k = 0; k < DIM; ++k) {
            float av = arow[k];
            float4 wa = *(const float4*)(WA + (size_t)k * DIM + j4);
            acc.x += av * wa.x;
            acc.y += av * wa.y;
            acc.z += av * wa.z;
            acc.w += av * wa.w;
        }
    }
    if (bias != nullptr) {
        float4 b = *(const float4*)(bias + j4);
        acc.x += b.x; acc.y += b.y; acc.z += b.z; acc.w += b.w;
    }
    if (doRelu) {
        acc.x = fmaxf(acc.x, 0.f);
        acc.y = fmaxf(acc.y, 0.f);
        acc.z = fmaxf(acc.z, 0.f);
        acc.w = fmaxf(acc.w, 0.f);
    }
    *(float4*)(out + (size_t)row * DIM + j4) = acc;
}

// ---------------------------------------------------------------------------
// Readout: batch is sorted with only NGR=32 graphs. Grid = NGR*RCHUNK blocks.
// Each block binary-searches its graph's row range, streams its chunk
// (no boundary checks), LDS-reduces 8 row-stripes, then 128 atomics/block.
__global__ __launch_bounds__(256) void readout_kernel(
    const float* __restrict__ xr, const int* __restrict__ batch,
    float* __restrict__ gsum, int nrows)
{
    __shared__ float lds[256 * 4];
    int g = blockIdx.x / RCHUNK;
    int chunk = blockIdx.x % RCHUNK;
    int lo = lbound(batch, nrows, g);
    int hi = lbound(batch, nrows, g + 1);
    int len = hi - lo;
    if (len == 0) return;
    int per = (len + RCHUNK - 1) / RCHUNK;
    int r0 = lo + chunk * per;
    int r1 = min(r0 + per, hi);

    int t = threadIdx.x;
    int c4 = (t & 31) << 2;
    int rsub = t >> 5;              // 0..7

    float4 acc = make_float4(0.f, 0.f, 0.f, 0.f);
    for (int r = r0 + rsub; r < r1; r += 8) {
        float4 v = *(const float4*)(xr + (size_t)r * DIM + c4);
        acc.x += v.x; acc.y += v.y; acc.z += v.z; acc.w += v.w;
    }
    *(float4*)(lds + t * 4) = acc;
    __syncthreads();
    if (rsub == 0) {
        float4 s = make_float4(0.f, 0.f, 0.f, 0.f);
        #pragma unroll
        for (int j = 0; j < 8; ++j) {
            float4 v = *(const float4*)(lds + (j * 32 + t) * 4);
            s.x += v.x; s.y += v.y; s.z += v.z; s.w += v.w;
        }
        atomicAdd(&gsum[(size_t)g * DIM + c4 + 0], s.x);
        atomicAdd(&gsum[(size_t)g * DIM + c4 + 1], s.y);
        atomicAdd(&gsum[(size_t)g * DIM + c4 + 2], s.z);
        atomicAdd(&gsum[(size_t)g * DIM + c4 + 3], s.w);
    }
}

__global__ __launch_bounds__(256) void finalize_kernel(
    const float* __restrict__ gsum, const int* __restrict__ batch,
    float* __restrict__ out, int nrows)
{
    int idx = blockIdx.x * 256 + threadIdx.x;
    if (idx >= NGR * DIM) return;
    int g = idx >> 7;
    int lo = lbound(batch, nrows, g);
    int hi = lbound(batch, nrows, g + 1);
    float c = fmaxf((float)(hi - lo), 1.f);
    out[idx] = gsum[idx] / c;
}

// ---------------------------------------------------------------------------
extern "C" void kernel_launch(void* const* d_in, const int* in_sizes, int n_in,
                              void* d_out, int out_size, void* d_ws, size_t ws_size,
                              hipStream_t stream)
{
    const float* x_real    = (const float*)d_in[0];
    const float* x_virtual = (const float*)d_in[1];
    const float* W_root    = (const float*)d_in[2];
    const float* W_nbr     = (const float*)d_in[3];
    const float* bias      = (const float*)d_in[4];
    const int*   edge_rr   = (const int*)d_in[5];   // [2, E_RR]
    const int*   edge_rv   = (const int*)d_in[6];   // [2, N_R] row0=arange row1=vmap
    const int*   edge_vr   = (const int*)d_in[7];   // [2, N_R] row0=vmap  row1=arange
    const int*   batch     = (const int*)d_in[8];   // [N_R] sorted

    float* out = (float*)d_out;                     // [N_R*DIM] + [NGR*DIM]

    // ---- workspace layout ----
    float* ws   = (float*)d_ws;
    float* Arv  = ws;                               // N_V*DIM
    float* Tv   = Arv  + (size_t)N_V * DIM;
    float* xv_a = Tv   + (size_t)N_V * DIM;
    float* xv_b = xv_a + (size_t)N_V * DIM;
    float* bc   = xv_b + (size_t)N_V * DIM;         // NLAY*DIM
    float* gsum = bc   + (size_t)NLAY * DIM;        // NGR*DIM
    float* gcnt = gsum + (size_t)NGR * DIM;         // NGR (unused now)
    ushort* xrb_in = (ushort*)(gcnt + NGR);         // N_R*DIM bf16
    ushort* xrb_a  = xrb_in + (size_t)N_R * DIM;
    ushort* xrb_b  = xrb_a  + (size_t)N_R * DIM;
    ushort* ArrB   = xrb_b  + (size_t)N_R * DIM;    // N_R*DIM bf16
    ushort* WT     = ArrB   + (size_t)N_R * DIM;    // NLAY*128*256 bf16
    int* iws       = (int*)(WT + (size_t)NLAY * DIM * 2 * DIM);
    int* cnt_r     = iws;                           // N_R
    int* rowptr_rr = cnt_r + N_R;                   // N_R+1
    int* cursor_rr = rowptr_rr + N_R + 1;           // N_R
    int* col_rr    = cursor_rr + N_R;               // E_RR
    int* cnt_v     = col_rr + E_RR;                 // N_V
    int* rowptr_rv = cnt_v + N_V;                   // N_V+1
    int* cursor_rv = rowptr_rv + N_V + 1;           // N_V
    int* col_rv    = cursor_rv + N_V;               // N_R
    int* incl      = col_rv + N_R;                  // N_R (scan temp)
    int* bsum      = incl + N_R;                    // 256 (scan temp)

    const int* rr_src = edge_rr;
    const int* rr_dst = edge_rr + E_RR;
    const int* rv_src = edge_rv;
    const int* rv_dst = edge_rv + N_R;

    const int nbR = (N_R + 255) / 256;
    const int nbV = (N_V + 255) / 256;

    // CSR build (reused across layers)
    hipMemsetAsync(cnt_r, 0, (size_t)N_R * sizeof(int), stream);
    hipMemsetAsync(cnt_v, 0, (size_t)N_V * sizeof(int), stream);
    hist_kernel<<<(E_RR + 255) / 256, 256, 0, stream>>>(rr_dst, E_RR, cnt_r);
    hist_kernel<<<(N_R + 255) / 256, 256, 0, stream>>>(rv_dst, N_R, cnt_v);

    scan1_kernel<<<nbR, 256, 0, stream>>>(cnt_r, N_R, incl, bsum);
    scan2_kernel<<<1, 256, 0, stream>>>(bsum, nbR);
    scan3_kernel<<<nbR, 256, 0, stream>>>(cnt_r, incl, bsum, N_R, E_RR,
                                          rowptr_rr, cursor_rr);
    scan1_kernel<<<nbV, 256, 0, stream>>>(cnt_v, N_V, incl, bsum);
    scan2_kernel<<<1, 256, 0, stream>>>(bsum, nbV);
    scan3_kernel<<<nbV, 256, 0, stream>>>(cnt_v, incl, bsum, N_V, N_R,
                                          rowptr_rv, cursor_rv);

    fill_kernel<<<(E_RR + 255) / 256, 256, 0, stream>>>(rr_src, rr_dst, E_RR, cursor_rr, col_rr);
    fill_kernel<<<(N_R + 255) / 256, 256, 0, stream>>>(rv_src, rv_dst, N_R, cursor_rv, col_rv);

    // weights/bias prep + input conversion
    build_wt_kernel<<<(NLAY * DIM * 2 * DIM + 255) / 256, 256, 0, stream>>>(W_root, W_nbr, WT);
    combine_b_kernel<<<(NLAY * DIM + 255) / 256, 256, 0, stream>>>(bias, bc);
    conv_bf16_kernel<<<(N_R * DIM / 4 + 255) / 256, 256, 0, stream>>>(x_real, xrb_in, N_R * DIM / 4);

    const ushort* cur_xrb = xrb_in;
    const float*  cur_xv  = x_virtual;

    for (int l = 0; l < NLAY; ++l) {
        const float* Wn1 = W_nbr + ((size_t)l * 3 + 1) * DIM * DIM;  // r->v nbr
        const float* Wn2 = W_nbr + ((size_t)l * 3 + 2) * DIM * DIM;  // v->r nbr
        const float* Wr1 = W_root + ((size_t)l * 3 + 1) * DIM * DIM; // v root
        const float* b1  = bias + ((size_t)l * 3 + 1) * DIM;

        // A_rr[d] = sum x_r[src]  (bf16 gather, bf16 out)
        agg_kernel<<<(N_R * 64 + 255) / 256, 256, 0, stream>>>(
            rowptr_rr, col_rr, cur_xrb, ArrB, nullptr, N_R);

        // T_v = x_v @ Wn2 (fp32)
        gemm_kernel<<<(N_V + 7) / 8, 256, 0, stream>>>(
            cur_xv, Wn2, nullptr, nullptr, nullptr, Tv, N_V, 0);

        // x_r_new = relu( [x_r|A_rr] @ WT_l + Tv[vmap] + bc_l )
        ushort* xrb_out = (l == 0) ? xrb_a : ((l == 1) ? xrb_b : nullptr);
        float*  outF    = (l == NLAY - 1) ? out : nullptr;
        mfma_gemm_kernel<<<(N_R + 63) / 64, 256, 0, stream>>>(
            cur_xrb, ArrB, WT + (size_t)l * DIM * 2 * DIM,
            Tv, edge_vr, bc + (size_t)l * DIM, outF, xrb_out, N_R);

        if (l < NLAY - 1) {
            // A_rv[v] = sum x_r[r] over r with vmap[r]=v (fp32 out, uses layer input)
            agg_kernel<<<(N_V * 64 + 255) / 256, 256, 0, stream>>>(
                rowptr_rv, col_rv, cur_xrb, nullptr, Arv, N_V);
            // x_v_new = relu( x_v @ Wr1 + A_rv @ Wn1 + b1 )
            float* xv_out = (l & 1) ? xv_b : xv_a;
            gemm_kernel<<<(N_V + 7) / 8, 256, 0, stream>>>(
                cur_xv, Wr1, Arv, Wn1, b1, xv_out, N_V, 1);
            cur_xv = xv_out;
        }
        cur_xrb = xrb_out;
    }

    // readout: mean over real nodes per graph (binary-search segments)
    hipMemsetAsync(gsum, 0, (size_t)NGR * DIM * sizeof(float), stream);
    readout_kernel<<<NGR * RCHUNK, 256, 0, stream>>>(out, batch, gsum, N_R);
    finalize_kernel<<<(NGR * DIM + 255) / 256, 256, 0, stream>>>(
        gsum, batch, out + (size_t)N_R * DIM, N_R);
}

// Round 7
// 463.180 us; speedup vs baseline: 11.0497x; 1.1741x over previous
//
#include <hip/hip_runtime.h>
#include <hip/hip_bf16.h>

// Problem constants (fixed by the reference setup_inputs()):
#define N_R   50000
#define N_V   2000
#define DIM   128
#define E_RR  800000
#define NLAY  3
#define NGR   32
#define RCHUNK 16   // readout chunks per graph

// bucket-CSR constants: bucket = dst>>7 (128 dsts/bucket), chunk = 2048 edges
#define BUKD  128
#define NBUK  391   // ceil(50000/128)
#define CHKE  2048
#define NCHK  391   // ceil(800000/2048)

typedef __attribute__((ext_vector_type(8))) short bf16x8;
typedef __attribute__((ext_vector_type(4))) float f32x4;

__device__ __forceinline__ ushort f2bf(float f) {
    unsigned u = __builtin_bit_cast(unsigned, f);
    unsigned r = (u + 0x7fffu + ((u >> 16) & 1u)) >> 16;   // RNE
    return (ushort)r;
}
__device__ __forceinline__ float bf2f(ushort h) {
    unsigned u = ((unsigned)h) << 16;
    return __builtin_bit_cast(float, u);
}
__device__ __forceinline__ int lbound(const int* __restrict__ a, int n, int key) {
    int lo = 0, hi = n;
    while (lo < hi) { int mid = (lo + hi) >> 1; if (a[mid] < key) lo = mid + 1; else hi = mid; }
    return lo;
}

// ---------------------------------------------------------------------------
// small-relation CSR build (rv): histogram -> scan -> fill (50K atomics, cheap)
__global__ __launch_bounds__(256) void hist_kernel(
    const int* __restrict__ dst, int n, int* __restrict__ cnt)
{
    int i = blockIdx.x * 256 + threadIdx.x;
    if (i < n) atomicAdd(&cnt[dst[i]], 1);
}

__global__ __launch_bounds__(256) void scan1_kernel(
    const int* __restrict__ cnt, int n,
    int* __restrict__ incl, int* __restrict__ bsum)
{
    __shared__ int lds[256];
    int t = threadIdx.x;
    int i = blockIdx.x * 256 + t;
    int v = (i < n) ? cnt[i] : 0;
    lds[t] = v;
    __syncthreads();
    #pragma unroll
    for (int off = 1; off < 256; off <<= 1) {
        int u = (t >= off) ? lds[t - off] : 0;
        __syncthreads();
        lds[t] += u;
        __syncthreads();
    }
    if (i < n) incl[i] = lds[t];
    if (t == 255) bsum[blockIdx.x] = lds[255];
}

__global__ __launch_bounds__(256) void scan2_kernel(
    int* __restrict__ bsum, int nb)
{
    __shared__ int lds[256];
    int t = threadIdx.x;
    int v = (t < nb) ? bsum[t] : 0;
    lds[t] = v;
    __syncthreads();
    #pragma unroll
    for (int off = 1; off < 256; off <<= 1) {
        int u = (t >= off) ? lds[t - off] : 0;
        __syncthreads();
        lds[t] += u;
        __syncthreads();
    }
    if (t < nb) bsum[t] = lds[t] - v;   // exclusive
}

__global__ __launch_bounds__(256) void scan3_kernel(
    const int* __restrict__ cnt, const int* __restrict__ incl,
    const int* __restrict__ bsum, int n, int nedges,
    int* __restrict__ rowptr, int* __restrict__ cursor)
{
    int i = blockIdx.x * 256 + threadIdx.x;
    if (i < n) {
        int e = incl[i] - cnt[i] + bsum[blockIdx.x];
        rowptr[i] = e;
        cursor[i] = e;
    }
    if (i == 0) rowptr[n] = nedges;
}

__global__ __launch_bounds__(256) void fill_kernel(
    const int* __restrict__ src, const int* __restrict__ dst, int n,
    int* __restrict__ cursor, int* __restrict__ col)
{
    int i = blockIdx.x * 256 + threadIdx.x;
    if (i < n) {
        int p = atomicAdd(&cursor[dst[i]], 1);
        col[p] = src[i];
    }
}

// ---------------------------------------------------------------------------
// Bucket-CSR build for the big rr relation (LDS atomics only).
// K1: per-chunk LDS histogram over NBUK coarse buckets
__global__ __launch_bounds__(256) void bkt_count_kernel(
    const int* __restrict__ dst, int* __restrict__ cnt2d)
{
    __shared__ int h[NBUK];
    int t = threadIdx.x, c = blockIdx.x;
    for (int i = t; i < NBUK; i += 256) h[i] = 0;
    __syncthreads();
    int e0 = c * CHKE, e1 = min(e0 + CHKE, E_RR);
    for (int e = e0 + t; e < e1; e += 256) atomicAdd(&h[dst[e] >> 7], 1);
    __syncthreads();
    for (int i = t; i < NBUK; i += 256) cnt2d[(size_t)c * NBUK + i] = h[i];
}

// K2: per-bucket prefix over chunks (wave scan) -> rel2d, tot
__global__ __launch_bounds__(64) void bkt_prefix_kernel(
    const int* __restrict__ cnt2d, int* __restrict__ rel2d, int* __restrict__ tot)
{
    int b = blockIdx.x, lane = threadIdx.x;
    int base = 0;
    for (int c0 = 0; c0 < NCHK; c0 += 64) {
        int c = c0 + lane;
        int v = (c < NCHK) ? cnt2d[(size_t)c * NBUK + b] : 0;
        int s = v;
        #pragma unroll
        for (int off = 1; off < 64; off <<= 1) {
            int u = __shfl_up(s, off);
            if (lane >= off) s += u;
        }
        if (c < NCHK) rel2d[(size_t)c * NBUK + b] = base + s - v;
        base += __shfl(s, 63);
    }
    if (lane == 0) tot[b] = base;
}

// K3: partition edges into bucket-sorted ebuf (packed (dst<<16)|src)
__global__ __launch_bounds__(256) void bkt_scatter_kernel(
    const int* __restrict__ src, const int* __restrict__ dst,
    const int* __restrict__ rel2d, const int* __restrict__ bstart,
    unsigned* __restrict__ ebuf)
{
    __shared__ int cur[NBUK];
    int t = threadIdx.x, c = blockIdx.x;
    for (int i = t; i < NBUK; i += 256)
        cur[i] = bstart[i] + rel2d[(size_t)c * NBUK + i];
    __syncthreads();
    int e0 = c * CHKE, e1 = min(e0 + CHKE, E_RR);
    for (int e = e0 + t; e < e1; e += 256) {
        int d = dst[e];
        int p = atomicAdd(&cur[d >> 7], 1);
        ebuf[p] = ((unsigned)d << 16) | (unsigned)src[e];
    }
}

// K4: per-bucket fine CSR (128-bin LDS count + scan) -> rowptr, col
__global__ __launch_bounds__(256) void bkt_fine_kernel(
    const unsigned* __restrict__ ebuf, const int* __restrict__ bstart,
    int* __restrict__ rowptr, int* __restrict__ col)
{
    __shared__ int cnt[BUKD];
    __shared__ int sc[BUKD];
    __shared__ int cur[BUKD];
    int b = blockIdx.x, t = threadIdx.x;
    int s0 = bstart[b], s1 = bstart[b + 1];
    if (t < BUKD) cnt[t] = 0;
    __syncthreads();
    for (int e = s0 + t; e < s1; e += 256)
        atomicAdd(&cnt[(ebuf[e] >> 16) & (BUKD - 1)], 1);
    __syncthreads();
    if (t < BUKD) sc[t] = cnt[t];
    __syncthreads();
    #pragma unroll
    for (int off = 1; off < BUKD; off <<= 1) {
        int v = (t < BUKD && t >= off) ? sc[t - off] : 0;
        __syncthreads();
        if (t < BUKD) sc[t] += v;
        __syncthreads();
    }
    if (t < BUKD) {
        int ex = sc[t] - cnt[t];
        int d = b * BUKD + t;
        if (d < N_R) rowptr[d] = s0 + ex;
        cur[t] = ex;
    }
    if (b == NBUK - 1 && t == 0) rowptr[N_R] = E_RR;
    __syncthreads();
    for (int e = s0 + t; e < s1; e += 256) {
        unsigned pk = ebuf[e];
        int p = atomicAdd(&cur[(pk >> 16) & (BUKD - 1)], 1);
        col[s0 + p] = (int)(pk & 0xffffu);
    }
}

// ---------------------------------------------------------------------------
// Convert fp32 matrix to bf16
__global__ __launch_bounds__(256) void conv_bf16_kernel(
    const float* __restrict__ in, ushort* __restrict__ out, int n4)
{
    int i = blockIdx.x * 256 + threadIdx.x;
    if (i >= n4) return;
    float4 v = *(const float4*)(in + (size_t)i * 4);
    ushort4 o;
    o.x = f2bf(v.x); o.y = f2bf(v.y); o.z = f2bf(v.z); o.w = f2bf(v.w);
    *(ushort4*)(out + (size_t)i * 4) = o;
}

// ---------------------------------------------------------------------------
// Build per-layer bf16 weight blocks, n-major:
//   WT[l][n][k] : k<128 -> Wroot[l,0,k,n]+Wroot[l,2,k,n] ; k>=128 -> Wnbr[l,0,k-128,n]
__global__ __launch_bounds__(256) void build_wt_kernel(
    const float* __restrict__ Wroot, const float* __restrict__ Wnbr,
    ushort* __restrict__ WT)
{
    int idx = blockIdx.x * 256 + threadIdx.x;
    if (idx >= NLAY * DIM * 2 * DIM) return;
    int k = idx & 255;
    int n = (idx >> 8) & 127;
    int l = idx >> 15;
    float v;
    if (k < DIM) {
        const float* base = Wroot + (size_t)l * 3 * DIM * DIM;
        v = base[(size_t)k * DIM + n] + base[(size_t)(2 * DIM + k) * DIM + n];
    } else {
        v = Wnbr[((size_t)l * 3 * DIM + (k - DIM)) * DIM + n];
    }
    WT[idx] = f2bf(v);
}

__global__ __launch_bounds__(256) void combine_b_kernel(
    const float* __restrict__ bias, float* __restrict__ bc)
{
    int idx = blockIdx.x * 256 + threadIdx.x;
    if (idx >= NLAY * DIM) return;
    int l = idx / DIM;
    int rest = idx - l * DIM;
    const float* base = bias + (size_t)l * 3 * DIM;
    bc[idx] = base[rest] + base[2 * DIM + rest];
}

// ---------------------------------------------------------------------------
// Gather-aggregate over bf16 features: out[d][:] = sum x[col[i]][:]
__global__ __launch_bounds__(256) void agg_kernel(
    const int* __restrict__ rowptr, const int* __restrict__ col,
    const ushort* __restrict__ x, ushort* __restrict__ outB,
    float* __restrict__ outF, int nrows)
{
    int gid = blockIdx.x * 256 + threadIdx.x;
    int w = gid >> 6;
    int lane = gid & 63;
    if (w >= nrows) return;
    int beg = rowptr[w], end = rowptr[w + 1];
    float ax = 0.f, ay = 0.f;
    int i = beg;
    for (; i + 1 < end; i += 2) {
        int s0 = col[i], s1 = col[i + 1];
        unsigned v0 = *(const unsigned*)(x + (size_t)s0 * DIM + lane * 2);
        unsigned v1 = *(const unsigned*)(x + (size_t)s1 * DIM + lane * 2);
        ax += bf2f((ushort)(v0 & 0xffff)) + bf2f((ushort)(v1 & 0xffff));
        ay += bf2f((ushort)(v0 >> 16))    + bf2f((ushort)(v1 >> 16));
    }
    if (i < end) {
        unsigned v0 = *(const unsigned*)(x + (size_t)col[i] * DIM + lane * 2);
        ax += bf2f((ushort)(v0 & 0xffff));
        ay += bf2f((ushort)(v0 >> 16));
    }
    if (outB) {
        unsigned o = (unsigned)f2bf(ax) | ((unsigned)f2bf(ay) << 16);
        *(unsigned*)(outB + (size_t)w * DIM + lane * 2) = o;
    }
    if (outF) {
        *(float2*)(outF + (size_t)w * DIM + lane * 2) = make_float2(ax, ay);
    }
}

// ---------------------------------------------------------------------------
// MFMA GEMM for the real-node update:
//   C[M][128] = relu( [A1|A2] @ W  + Tv[vmap[row]]  + bias ),  K = 256
// Wave tile 16 rows x 64 cols; block = 4 waves = 32 rows x 128 cols.
__global__ __launch_bounds__(256) void mfma_gemm_kernel(
    const ushort* __restrict__ A1, const ushort* __restrict__ A2,
    const ushort* __restrict__ WT, const float* __restrict__ Tv,
    const int* __restrict__ vmap, const float* __restrict__ bias,
    float* __restrict__ outF, ushort* __restrict__ outB, int M)
{
    int wave = threadIdx.x >> 6;
    int lane = threadIdx.x & 63;
    int wr = wave >> 1;           // row half (0..1)
    int wc = wave & 1;            // col half (0..1)
    int rlo = lane & 15;
    int hi = lane >> 4;
    int row0 = blockIdx.x * 32 + wr * 16;
    int arow = row0 + rlo;
    int arowc = min(arow, M - 1);

    // preload 8 A-fragments: frag j covers k = 32j + 8*hi .. +7
    bf16x8 afr[8];
    #pragma unroll
    for (int j = 0; j < 8; ++j) {
        int k = 32 * j + 8 * hi;
        const ushort* src = (k < DIM)
            ? (A1 + (size_t)arowc * DIM + k)
            : (A2 + (size_t)arowc * DIM + (k - DIM));
        afr[j] = *(const bf16x8*)src;
    }

    f32x4 acc[4];
    #pragma unroll
    for (int n = 0; n < 4; ++n) acc[n] = (f32x4){0.f, 0.f, 0.f, 0.f};

    #pragma unroll
    for (int n = 0; n < 4; ++n) {
        int nt = wc * 4 + n;      // n-tile index 0..7
        const ushort* wrow = WT + (size_t)(nt * 16 + rlo) * (2 * DIM);
        #pragma unroll
        for (int j = 0; j < 8; ++j) {
            bf16x8 bfr = *(const bf16x8*)(wrow + 32 * j + 8 * hi);
            acc[n] = __builtin_amdgcn_mfma_f32_16x16x32_bf16(afr[j], bfr, acc[n], 0, 0, 0);
        }
    }

    // epilogue: C row = row0 + 4*hi + i, col = (wc*4+n)*16 + rlo
    const float* tvp[4];
    #pragma unroll
    for (int i = 0; i < 4; ++i) {
        int orow = row0 + 4 * hi + i;
        tvp[i] = (Tv != nullptr && orow < M)
                 ? (Tv + (size_t)vmap[orow] * DIM) : nullptr;
    }
    #pragma unroll
    for (int n = 0; n < 4; ++n) {
        int ncol = (wc * 4 + n) * 16 + rlo;
        float bv = bias[ncol];
        #pragma unroll
        for (int i = 0; i < 4; ++i) {
            int orow = row0 + 4 * hi + i;
            if (orow >= M) continue;
            float v = acc[n][i] + bv;
            if (tvp[i]) v += tvp[i][ncol];
            v = fmaxf(v, 0.f);
            if (outF) outF[(size_t)orow * DIM + ncol] = v;
            if (outB) outB[(size_t)orow * DIM + ncol] = f2bf(v);
        }
    }
}

// ---------------------------------------------------------------------------
// Small fp32 GEMM (virtual-node paths, N_V rows)
__global__ __launch_bounds__(256) void gemm_kernel(
    const float* __restrict__ A,  const float* __restrict__ WA,
    const float* __restrict__ B,  const float* __restrict__ WB,
    const float* __restrict__ bias, float* __restrict__ out,
    int nrows, int doRelu)
{
    int t = threadIdx.x;
    int localRow = t >> 5;
    int j4 = (t & 31) << 2;
    int row = blockIdx.x * 8 + localRow;
    if (row >= nrows) return;

    float4 acc = make_float4(0.f, 0.f, 0.f, 0.f);
    const float* arow = A + (size_t)row * DIM;

    if (B != nullptr) {
        const float* brow = B + (size_t)row * DIM;
        #pragma unroll 8
        for (int k = 0; k < DIM; ++k) {
            float av = arow[k];
            float bv = brow[k];
            float4 wa = *(const float4*)(WA + (size_t)k * DIM + j4);
            float4 wb = *(const float4*)(WB + (size_t)k * DIM + j4);
            acc.x += av * wa.x + bv * wb.x;
            acc.y += av * wa.y + bv * wb.y;
            acc.z += av * wa.z + bv * wb.z;
            acc.w += av * wa.w + bv * wb.w;
        }
    } else {
        #pragma unroll 8
        for (int k = 0; k < DIM; ++k) {
            float av = arow[k];
            float4 wa = *(const float4*)(WA + (size_t)k * DIM + j4);
            acc.x += av * wa.x;
            acc.y += av * wa.y;
            acc.z += av * wa.z;
            acc.w += av * wa.w;
        }
    }
    if (bias != nullptr) {
        float4 b = *(const float4*)(bias + j4);
        acc.x += b.x; acc.y += b.y; acc.z += b.z; acc.w += b.w;
    }
    if (doRelu) {
        acc.x = fmaxf(acc.x, 0.f);
        acc.y = fmaxf(acc.y, 0.f);
        acc.z = fmaxf(acc.z, 0.f);
        acc.w = fmaxf(acc.w, 0.f);
    }
    *(float4*)(out + (size_t)row * DIM + j4) = acc;
}

// ---------------------------------------------------------------------------
// Readout: batch sorted, NGR=32 graphs. Block binary-searches its segment.
__global__ __launch_bounds__(256) void readout_kernel(
    const float* __restrict__ xr, const int* __restrict__ batch,
    float* __restrict__ gsum, int nrows)
{
    __shared__ float lds[256 * 4];
    int g = blockIdx.x / RCHUNK;
    int chunk = blockIdx.x % RCHUNK;
    int lo = lbound(batch, nrows, g);
    int hi = lbound(batch, nrows, g + 1);
    int len = hi - lo;
    if (len == 0) return;
    int per = (len + RCHUNK - 1) / RCHUNK;
    int r0 = lo + chunk * per;
    int r1 = min(r0 + per, hi);

    int t = threadIdx.x;
    int c4 = (t & 31) << 2;
    int rsub = t >> 5;

    float4 acc = make_float4(0.f, 0.f, 0.f, 0.f);
    for (int r = r0 + rsub; r < r1; r += 8) {
        float4 v = *(const float4*)(xr + (size_t)r * DIM + c4);
        acc.x += v.x; acc.y += v.y; acc.z += v.z; acc.w += v.w;
    }
    *(float4*)(lds + t * 4) = acc;
    __syncthreads();
    if (rsub == 0) {
        float4 s = make_float4(0.f, 0.f, 0.f, 0.f);
        #pragma unroll
        for (int j = 0; j < 8; ++j) {
            float4 v = *(const float4*)(lds + (j * 32 + t) * 4);
            s.x += v.x; s.y += v.y; s.z += v.z; s.w += v.w;
        }
        atomicAdd(&gsum[(size_t)g * DIM + c4 + 0], s.x);
        atomicAdd(&gsum[(size_t)g * DIM + c4 + 1], s.y);
        atomicAdd(&gsum[(size_t)g * DIM + c4 + 2], s.z);
        atomicAdd(&gsum[(size_t)g * DIM + c4 + 3], s.w);
    }
}

__global__ __launch_bounds__(256) void finalize_kernel(
    const float* __restrict__ gsum, const int* __restrict__ batch,
    float* __restrict__ out, int nrows)
{
    int idx = blockIdx.x * 256 + threadIdx.x;
    if (idx >= NGR * DIM) return;
    int g = idx >> 7;
    int lo = lbound(batch, nrows, g);
    int hi = lbound(batch, nrows, g + 1);
    float c = fmaxf((float)(hi - lo), 1.f);
    out[idx] = gsum[idx] / c;
}

// ---------------------------------------------------------------------------
extern "C" void kernel_launch(void* const* d_in, const int* in_sizes, int n_in,
                              void* d_out, int out_size, void* d_ws, size_t ws_size,
                              hipStream_t stream)
{
    const float* x_real    = (const float*)d_in[0];
    const float* x_virtual = (const float*)d_in[1];
    const float* W_root    = (const float*)d_in[2];
    const float* W_nbr     = (const float*)d_in[3];
    const float* bias      = (const float*)d_in[4];
    const int*   edge_rr   = (const int*)d_in[5];   // [2, E_RR]
    const int*   edge_rv   = (const int*)d_in[6];   // [2, N_R] row0=arange row1=vmap
    const int*   edge_vr   = (const int*)d_in[7];   // [2, N_R] row0=vmap  row1=arange
    const int*   batch     = (const int*)d_in[8];   // [N_R] sorted

    float* out = (float*)d_out;                     // [N_R*DIM] + [NGR*DIM]

    // ---- workspace layout ----
    float* ws   = (float*)d_ws;
    float* Arv  = ws;                               // N_V*DIM
    float* Tv   = Arv  + (size_t)N_V * DIM;
    float* xv_a = Tv   + (size_t)N_V * DIM;
    float* xv_b = xv_a + (size_t)N_V * DIM;
    float* bc   = xv_b + (size_t)N_V * DIM;         // NLAY*DIM
    float* gsum = bc   + (size_t)NLAY * DIM;        // NGR*DIM
    ushort* xrb_in = (ushort*)(gsum + NGR * DIM);   // N_R*DIM bf16
    ushort* xrb_a  = xrb_in + (size_t)N_R * DIM;
    ushort* ArrB   = xrb_a  + (size_t)N_R * DIM;    // N_R*DIM bf16
    ushort* WT     = ArrB   + (size_t)N_R * DIM;    // NLAY*128*256 bf16
    int* iws       = (int*)(WT + (size_t)NLAY * DIM * 2 * DIM);
    int* rowptr_rr = iws;                           // N_R+1
    int* col_rr    = rowptr_rr + N_R + 1;           // E_RR
    int* cnt_v     = col_rr + E_RR;                 // N_V
    int* rowptr_rv = cnt_v + N_V;                   // N_V+1
    int* cursor_rv = rowptr_rv + N_V + 1;           // N_V
    int* col_rv    = cursor_rv + N_V;               // N_R
    int* incl      = col_rv + N_R;                  // max(N_V, NBUK)
    int* bsum      = incl + N_V;                    // 256
    int* cnt2d     = bsum + 256;                    // NCHK*NBUK
    int* rel2d     = cnt2d + NCHK * NBUK;           // NCHK*NBUK
    int* tot       = rel2d + NCHK * NBUK;           // NBUK
    int* bstart    = tot + NBUK;                    // NBUK+1
    int* bcur      = bstart + NBUK + 1;             // NBUK (dummy)
    unsigned* ebuf = (unsigned*)(bcur + NBUK);      // E_RR

    const int* rr_src = edge_rr;
    const int* rr_dst = edge_rr + E_RR;
    const int* rv_src = edge_rv;
    const int* rv_dst = edge_rv + N_R;

    // ---- rr CSR via LDS-bucket sort (no device-scope atomics) ----
    bkt_count_kernel<<<NCHK, 256, 0, stream>>>(rr_dst, cnt2d);
    bkt_prefix_kernel<<<NBUK, 64, 0, stream>>>(cnt2d, rel2d, tot);
    scan1_kernel<<<(NBUK + 255) / 256, 256, 0, stream>>>(tot, NBUK, incl, bsum);
    scan2_kernel<<<1, 256, 0, stream>>>(bsum, (NBUK + 255) / 256);
    scan3_kernel<<<(NBUK + 255) / 256, 256, 0, stream>>>(tot, incl, bsum, NBUK, E_RR,
                                                         bstart, bcur);
    bkt_scatter_kernel<<<NCHK, 256, 0, stream>>>(rr_src, rr_dst, rel2d, bstart, ebuf);
    bkt_fine_kernel<<<NBUK, 256, 0, stream>>>(ebuf, bstart, rowptr_rr, col_rr);

    // ---- rv CSR (small): hist -> scan -> fill ----
    const int nbV = (N_V + 255) / 256;
    hipMemsetAsync(cnt_v, 0, (size_t)N_V * sizeof(int), stream);
    hist_kernel<<<(N_R + 255) / 256, 256, 0, stream>>>(rv_dst, N_R, cnt_v);
    scan1_kernel<<<nbV, 256, 0, stream>>>(cnt_v, N_V, incl, bsum);
    scan2_kernel<<<1, 256, 0, stream>>>(bsum, nbV);
    scan3_kernel<<<nbV, 256, 0, stream>>>(cnt_v, incl, bsum, N_V, N_R,
                                          rowptr_rv, cursor_rv);
    fill_kernel<<<(N_R + 255) / 256, 256, 0, stream>>>(rv_src, rv_dst, N_R, cursor_rv, col_rv);

    // weights/bias prep + input conversion
    build_wt_kernel<<<(NLAY * DIM * 2 * DIM + 255) / 256, 256, 0, stream>>>(W_root, W_nbr, WT);
    combine_b_kernel<<<(NLAY * DIM + 255) / 256, 256, 0, stream>>>(bias, bc);
    conv_bf16_kernel<<<(N_R * DIM / 4 + 255) / 256, 256, 0, stream>>>(x_real, xrb_in, N_R * DIM / 4);

    const ushort* cur_xrb = xrb_in;
    const float*  cur_xv  = x_virtual;

    for (int l = 0; l < NLAY; ++l) {
        const float* Wn1 = W_nbr + ((size_t)l * 3 + 1) * DIM * DIM;  // r->v nbr
        const float* Wn2 = W_nbr + ((size_t)l * 3 + 2) * DIM * DIM;  // v->r nbr
        const float* Wr1 = W_root + ((size_t)l * 3 + 1) * DIM * DIM; // v root
        const float* b1  = bias + ((size_t)l * 3 + 1) * DIM;

        // A_rr[d] = sum x_r[src]  (bf16 gather, bf16 out)
        agg_kernel<<<(N_R * 64 + 255) / 256, 256, 0, stream>>>(
            rowptr_rr, col_rr, cur_xrb, ArrB, nullptr, N_R);

        // T_v = x_v @ Wn2 (fp32)
        gemm_kernel<<<(N_V + 7) / 8, 256, 0, stream>>>(
            cur_xv, Wn2, nullptr, nullptr, nullptr, Tv, N_V, 0);

        // x_r_new = relu( [x_r|A_rr] @ WT_l + Tv[vmap] + bc_l )
        ushort* xrb_out = (l == NLAY - 1) ? nullptr : ((l & 1) ? xrb_in : xrb_a);
        float*  outF    = (l == NLAY - 1) ? out : nullptr;
        mfma_gemm_kernel<<<(N_R + 31) / 32, 256, 0, stream>>>(
            cur_xrb, ArrB, WT + (size_t)l * DIM * 2 * DIM,
            Tv, edge_vr, bc + (size_t)l * DIM, outF, xrb_out, N_R);

        if (l < NLAY - 1) {
            // A_rv[v] = sum x_r[r] over r with vmap[r]=v (fp32 out, layer input)
            agg_kernel<<<(N_V * 64 + 255) / 256, 256, 0, stream>>>(
                rowptr_rv, col_rv, cur_xrb, nullptr, Arv, N_V);
            // x_v_new = relu( x_v @ Wr1 + A_rv @ Wn1 + b1 )
            float* xv_out = (l & 1) ? xv_b : xv_a;
            gemm_kernel<<<(N_V + 7) / 8, 256, 0, stream>>>(
                cur_xv, Wr1, Arv, Wn1, b1, xv_out, N_V, 1);
            cur_xv = xv_out;
        }
        cur_xrb = xrb_out;
    }

    // readout: mean over real nodes per graph (binary-search segments)
    hipMemsetAsync(gsum, 0, (size_t)NGR * DIM * sizeof(float), stream);
    readout_kernel<<<NGR * RCHUNK, 256, 0, stream>>>(out, batch, gsum, N_R);
    finalize_kernel<<<(NGR * DIM + 255) / 256, 256, 0, stream>>>(
        gsum, batch, out + (size_t)N_R * DIM, N_R);
}

// Round 8
// 408.391 us; speedup vs baseline: 12.5321x; 1.1342x over previous
//
#include <hip/hip_runtime.h>
#include <hip/hip_bf16.h>

// Problem constants (fixed by the reference setup_inputs()):
#define N_R   50000
#define N_V   2000
#define DIM   128
#define E_RR  800000
#define NLAY  3
#define NGR   32
#define RCHUNK 16   // readout chunks per graph

// bucket-CSR constants: bucket = dst>>7 (128 dsts/bucket), chunk = 2048 edges
#define BUKD  128
#define NBUK  391   // ceil(50000/128)
#define CHKE  2048
#define NCHK  391   // ceil(800000/2048)

typedef __attribute__((ext_vector_type(8))) short bf16x8;
typedef __attribute__((ext_vector_type(4))) float f32x4;

__device__ __forceinline__ ushort f2bf(float f) {
    unsigned u = __builtin_bit_cast(unsigned, f);
    unsigned r = (u + 0x7fffu + ((u >> 16) & 1u)) >> 16;   // RNE
    return (ushort)r;
}
__device__ __forceinline__ float bf2f(ushort h) {
    unsigned u = ((unsigned)h) << 16;
    return __builtin_bit_cast(float, u);
}
__device__ __forceinline__ int lbound(const int* __restrict__ a, int n, int key) {
    int lo = 0, hi = n;
    while (lo < hi) { int mid = (lo + hi) >> 1; if (a[mid] < key) lo = mid + 1; else hi = mid; }
    return lo;
}

// ---------------------------------------------------------------------------
// small-relation CSR build (rv): histogram -> scan -> fill (50K atomics, cheap)
__global__ __launch_bounds__(256) void hist_kernel(
    const int* __restrict__ dst, int n, int* __restrict__ cnt)
{
    int i = blockIdx.x * 256 + threadIdx.x;
    if (i < n) atomicAdd(&cnt[dst[i]], 1);
}

__global__ __launch_bounds__(256) void scan1_kernel(
    const int* __restrict__ cnt, int n,
    int* __restrict__ incl, int* __restrict__ bsum)
{
    __shared__ int lds[256];
    int t = threadIdx.x;
    int i = blockIdx.x * 256 + t;
    int v = (i < n) ? cnt[i] : 0;
    lds[t] = v;
    __syncthreads();
    #pragma unroll
    for (int off = 1; off < 256; off <<= 1) {
        int u = (t >= off) ? lds[t - off] : 0;
        __syncthreads();
        lds[t] += u;
        __syncthreads();
    }
    if (i < n) incl[i] = lds[t];
    if (t == 255) bsum[blockIdx.x] = lds[255];
}

__global__ __launch_bounds__(256) void scan2_kernel(
    int* __restrict__ bsum, int nb)
{
    __shared__ int lds[256];
    int t = threadIdx.x;
    int v = (t < nb) ? bsum[t] : 0;
    lds[t] = v;
    __syncthreads();
    #pragma unroll
    for (int off = 1; off < 256; off <<= 1) {
        int u = (t >= off) ? lds[t - off] : 0;
        __syncthreads();
        lds[t] += u;
        __syncthreads();
    }
    if (t < nb) bsum[t] = lds[t] - v;   // exclusive
}

__global__ __launch_bounds__(256) void scan3_kernel(
    const int* __restrict__ cnt, const int* __restrict__ incl,
    const int* __restrict__ bsum, int n, int nedges,
    int* __restrict__ rowptr, int* __restrict__ cursor)
{
    int i = blockIdx.x * 256 + threadIdx.x;
    if (i < n) {
        int e = incl[i] - cnt[i] + bsum[blockIdx.x];
        rowptr[i] = e;
        cursor[i] = e;
    }
    if (i == 0) rowptr[n] = nedges;
}

__global__ __launch_bounds__(256) void fill_kernel(
    const int* __restrict__ src, const int* __restrict__ dst, int n,
    int* __restrict__ cursor, int* __restrict__ col)
{
    int i = blockIdx.x * 256 + threadIdx.x;
    if (i < n) {
        int p = atomicAdd(&cursor[dst[i]], 1);
        col[p] = src[i];
    }
}

// ---------------------------------------------------------------------------
// Bucket-CSR build for the big rr relation (LDS atomics only).
__global__ __launch_bounds__(256) void bkt_count_kernel(
    const int* __restrict__ dst, int* __restrict__ cnt2d)
{
    __shared__ int h[NBUK];
    int t = threadIdx.x, c = blockIdx.x;
    for (int i = t; i < NBUK; i += 256) h[i] = 0;
    __syncthreads();
    int e0 = c * CHKE, e1 = min(e0 + CHKE, E_RR);
    for (int e = e0 + t; e < e1; e += 256) atomicAdd(&h[dst[e] >> 7], 1);
    __syncthreads();
    for (int i = t; i < NBUK; i += 256) cnt2d[(size_t)c * NBUK + i] = h[i];
}

__global__ __launch_bounds__(64) void bkt_prefix_kernel(
    const int* __restrict__ cnt2d, int* __restrict__ rel2d, int* __restrict__ tot)
{
    int b = blockIdx.x, lane = threadIdx.x;
    int base = 0;
    for (int c0 = 0; c0 < NCHK; c0 += 64) {
        int c = c0 + lane;
        int v = (c < NCHK) ? cnt2d[(size_t)c * NBUK + b] : 0;
        int s = v;
        #pragma unroll
        for (int off = 1; off < 64; off <<= 1) {
            int u = __shfl_up(s, off);
            if (lane >= off) s += u;
        }
        if (c < NCHK) rel2d[(size_t)c * NBUK + b] = base + s - v;
        base += __shfl(s, 63);
    }
    if (lane == 0) tot[b] = base;
}

__global__ __launch_bounds__(256) void bkt_scatter_kernel(
    const int* __restrict__ src, const int* __restrict__ dst,
    const int* __restrict__ rel2d, const int* __restrict__ bstart,
    unsigned* __restrict__ ebuf)
{
    __shared__ int cur[NBUK];
    int t = threadIdx.x, c = blockIdx.x;
    for (int i = t; i < NBUK; i += 256)
        cur[i] = bstart[i] + rel2d[(size_t)c * NBUK + i];
    __syncthreads();
    int e0 = c * CHKE, e1 = min(e0 + CHKE, E_RR);
    for (int e = e0 + t; e < e1; e += 256) {
        int d = dst[e];
        int p = atomicAdd(&cur[d >> 7], 1);
        ebuf[p] = ((unsigned)d << 16) | (unsigned)src[e];
    }
}

__global__ __launch_bounds__(256) void bkt_fine_kernel(
    const unsigned* __restrict__ ebuf, const int* __restrict__ bstart,
    int* __restrict__ rowptr, int* __restrict__ col)
{
    __shared__ int cnt[BUKD];
    __shared__ int sc[BUKD];
    __shared__ int cur[BUKD];
    int b = blockIdx.x, t = threadIdx.x;
    int s0 = bstart[b], s1 = bstart[b + 1];
    if (t < BUKD) cnt[t] = 0;
    __syncthreads();
    for (int e = s0 + t; e < s1; e += 256)
        atomicAdd(&cnt[(ebuf[e] >> 16) & (BUKD - 1)], 1);
    __syncthreads();
    if (t < BUKD) sc[t] = cnt[t];
    __syncthreads();
    #pragma unroll
    for (int off = 1; off < BUKD; off <<= 1) {
        int v = (t < BUKD && t >= off) ? sc[t - off] : 0;
        __syncthreads();
        if (t < BUKD) sc[t] += v;
        __syncthreads();
    }
    if (t < BUKD) {
        int ex = sc[t] - cnt[t];
        int d = b * BUKD + t;
        if (d < N_R) rowptr[d] = s0 + ex;
        cur[t] = ex;
    }
    if (b == NBUK - 1 && t == 0) rowptr[N_R] = E_RR;
    __syncthreads();
    for (int e = s0 + t; e < s1; e += 256) {
        unsigned pk = ebuf[e];
        int p = atomicAdd(&cur[(pk >> 16) & (BUKD - 1)], 1);
        col[s0 + p] = (int)(pk & 0xffffu);
    }
}

// ---------------------------------------------------------------------------
__global__ __launch_bounds__(256) void conv_bf16_kernel(
    const float* __restrict__ in, ushort* __restrict__ out, int n4)
{
    int i = blockIdx.x * 256 + threadIdx.x;
    if (i >= n4) return;
    float4 v = *(const float4*)(in + (size_t)i * 4);
    ushort4 o;
    o.x = f2bf(v.x); o.y = f2bf(v.y); o.z = f2bf(v.z); o.w = f2bf(v.w);
    *(ushort4*)(out + (size_t)i * 4) = o;
}

// WT[l][n][k] : k<128 -> Wroot[l,0,k,n]+Wroot[l,2,k,n] ; k>=128 -> Wnbr[l,0,k-128,n]
__global__ __launch_bounds__(256) void build_wt_kernel(
    const float* __restrict__ Wroot, const float* __restrict__ Wnbr,
    ushort* __restrict__ WT)
{
    int idx = blockIdx.x * 256 + threadIdx.x;
    if (idx >= NLAY * DIM * 2 * DIM) return;
    int k = idx & 255;
    int n = (idx >> 8) & 127;
    int l = idx >> 15;
    float v;
    if (k < DIM) {
        const float* base = Wroot + (size_t)l * 3 * DIM * DIM;
        v = base[(size_t)k * DIM + n] + base[(size_t)(2 * DIM + k) * DIM + n];
    } else {
        v = Wnbr[((size_t)l * 3 * DIM + (k - DIM)) * DIM + n];
    }
    WT[idx] = f2bf(v);
}

__global__ __launch_bounds__(256) void combine_b_kernel(
    const float* __restrict__ bias, float* __restrict__ bc)
{
    int idx = blockIdx.x * 256 + threadIdx.x;
    if (idx >= NLAY * DIM) return;
    int l = idx / DIM;
    int rest = idx - l * DIM;
    const float* base = bias + (size_t)l * 3 * DIM;
    bc[idx] = base[rest] + base[2 * DIM + rest];
}

// ---------------------------------------------------------------------------
// Gather-aggregate (kept for the small rv relation): out fp32
__global__ __launch_bounds__(256) void agg_kernel(
    const int* __restrict__ rowptr, const int* __restrict__ col,
    const ushort* __restrict__ x, float* __restrict__ outF, int nrows)
{
    int gid = blockIdx.x * 256 + threadIdx.x;
    int w = gid >> 6;
    int lane = gid & 63;
    if (w >= nrows) return;
    int beg = rowptr[w], end = rowptr[w + 1];
    float ax = 0.f, ay = 0.f;
    int i = beg;
    for (; i + 1 < end; i += 2) {
        int s0 = col[i], s1 = col[i + 1];
        unsigned v0 = *(const unsigned*)(x + (size_t)s0 * DIM + lane * 2);
        unsigned v1 = *(const unsigned*)(x + (size_t)s1 * DIM + lane * 2);
        ax += bf2f((ushort)(v0 & 0xffff)) + bf2f((ushort)(v1 & 0xffff));
        ay += bf2f((ushort)(v0 >> 16))    + bf2f((ushort)(v1 >> 16));
    }
    if (i < end) {
        unsigned v0 = *(const unsigned*)(x + (size_t)col[i] * DIM + lane * 2);
        ax += bf2f((ushort)(v0 & 0xffff));
        ay += bf2f((ushort)(v0 >> 16));
    }
    *(float2*)(outF + (size_t)w * DIM + lane * 2) = make_float2(ax, ay);
}

// ---------------------------------------------------------------------------
// FUSED layer kernel for real nodes:
//   A2[r] = sum_{e in CSR row r} X[col[e]]        (gather, LDS-staged)
//   C[r]  = relu( [X[r] | A2[r]] @ WT + Tv[vmap[r]] + bias )
// Block: 256 thr = 4 waves, 32 output rows. LDS tile XOR-swizzled.
__global__ __launch_bounds__(256) void fused_layer_kernel(
    const int* __restrict__ rowptr, const int* __restrict__ col,
    const ushort* __restrict__ X,  const ushort* __restrict__ WT,
    const float* __restrict__ Tv,  const int* __restrict__ vmap,
    const float* __restrict__ bias,
    float* __restrict__ outF, ushort* __restrict__ outB, int M)
{
    __shared__ ushort a2[32 * DIM];          // 8 KB, swizzled rows
    int t = threadIdx.x;

    // ---- phase 0: prefetch A1 fragments + vmap (latency hides under gather)
    int wave = t >> 6, lane = t & 63;
    int wr = wave >> 1, wc = wave & 1;
    int rlo = lane & 15, hi = lane >> 4;
    int row0 = blockIdx.x * 32 + wr * 16;
    int arowc = min(row0 + rlo, M - 1);
    bf16x8 afr[8];
    #pragma unroll
    for (int j = 0; j < 4; ++j)
        afr[j] = *(const bf16x8*)(X + (size_t)arowc * DIM + 32 * j + 8 * hi);
    int vr[4];
    #pragma unroll
    for (int i = 0; i < 4; ++i)
        vr[i] = vmap[min(row0 + 4 * hi + i, M - 1)];

    // ---- phase 1: gather A2 rows into LDS (16-thread groups, 16B loads)
    int g = t >> 4;                          // 0..15
    int li = t & 15;
    for (int rr = g; rr < 32; rr += 16) {
        int drow = min(blockIdx.x * 32 + rr, M - 1);
        int beg = rowptr[drow], end = rowptr[drow + 1];
        float acc[8] = {0.f,0.f,0.f,0.f,0.f,0.f,0.f,0.f};
        int e = beg;
        for (; e + 1 < end; e += 2) {
            int s0 = col[e], s1 = col[e + 1];
            bf16x8 v0 = *(const bf16x8*)(X + (size_t)s0 * DIM + li * 8);
            bf16x8 v1 = *(const bf16x8*)(X + (size_t)s1 * DIM + li * 8);
            #pragma unroll
            for (int q = 0; q < 8; ++q)
                acc[q] += bf2f((ushort)v0[q]) + bf2f((ushort)v1[q]);
        }
        if (e < end) {
            int s0 = col[e];
            bf16x8 v0 = *(const bf16x8*)(X + (size_t)s0 * DIM + li * 8);
            #pragma unroll
            for (int q = 0; q < 8; ++q) acc[q] += bf2f((ushort)v0[q]);
        }
        bf16x8 pk;
        #pragma unroll
        for (int q = 0; q < 8; ++q) pk[q] = (short)f2bf(acc[q]);
        int byte = rr * 256 + ((li * 16) ^ ((rr & 7) << 4));
        *(bf16x8*)((char*)a2 + byte) = pk;
    }
    __syncthreads();

    // ---- phase 2: A2 fragments from LDS, MFMA, fused epilogue
    int lrow = wr * 16 + rlo;
    #pragma unroll
    for (int jj = 0; jj < 4; ++jj) {
        int byte = lrow * 256 + ((64 * jj + 16 * hi) ^ ((lrow & 7) << 4));
        afr[4 + jj] = *(const bf16x8*)((const char*)a2 + byte);
    }

    f32x4 acc[4];
    #pragma unroll
    for (int n = 0; n < 4; ++n) acc[n] = (f32x4){0.f, 0.f, 0.f, 0.f};

    #pragma unroll
    for (int n = 0; n < 4; ++n) {
        int nt = wc * 4 + n;                 // n-tile 0..7
        const ushort* wrow = WT + (size_t)(nt * 16 + rlo) * (2 * DIM);
        #pragma unroll
        for (int j = 0; j < 8; ++j) {
            bf16x8 bfr = *(const bf16x8*)(wrow + 32 * j + 8 * hi);
            acc[n] = __builtin_amdgcn_mfma_f32_16x16x32_bf16(afr[j], bfr, acc[n], 0, 0, 0);
        }
    }

    // epilogue: C row = row0 + 4*hi + i, col = (wc*4+n)*16 + rlo
    #pragma unroll
    for (int n = 0; n < 4; ++n) {
        int ncol = (wc * 4 + n) * 16 + rlo;
        float bv = bias[ncol];
        #pragma unroll
        for (int i = 0; i < 4; ++i) {
            int orow = row0 + 4 * hi + i;
            if (orow >= M) continue;
            float v = acc[n][i] + bv + Tv[(size_t)vr[i] * DIM + ncol];
            v = fmaxf(v, 0.f);
            if (outF) outF[(size_t)orow * DIM + ncol] = v;
            if (outB) outB[(size_t)orow * DIM + ncol] = f2bf(v);
        }
    }
}

// ---------------------------------------------------------------------------
// Small fp32 GEMM (virtual-node paths, N_V rows)
__global__ __launch_bounds__(256) void gemm_kernel(
    const float* __restrict__ A,  const float* __restrict__ WA,
    const float* __restrict__ B,  const float* __restrict__ WB,
    const float* __restrict__ bias, float* __restrict__ out,
    int nrows, int doRelu)
{
    int t = threadIdx.x;
    int localRow = t >> 5;
    int j4 = (t & 31) << 2;
    int row = blockIdx.x * 8 + localRow;
    if (row >= nrows) return;

    float4 acc = make_float4(0.f, 0.f, 0.f, 0.f);
    const float* arow = A + (size_t)row * DIM;

    if (B != nullptr) {
        const float* brow = B + (size_t)row * DIM;
        #pragma unroll 8
        for (int k = 0; k < DIM; ++k) {
            float av = arow[k];
            float bv = brow[k];
            float4 wa = *(const float4*)(WA + (size_t)k * DIM + j4);
            float4 wb = *(const float4*)(WB + (size_t)k * DIM + j4);
            acc.x += av * wa.x + bv * wb.x;
            acc.y += av * wa.y + bv * wb.y;
            acc.z += av * wa.z + bv * wb.z;
            acc.w += av * wa.w + bv * wb.w;
        }
    } else {
        #pragma unroll 8
        for (int k = 0; k < DIM; ++k) {
            float av = arow[k];
            float4 wa = *(const float4*)(WA + (size_t)k * DIM + j4);
            acc.x += av * wa.x;
            acc.y += av * wa.y;
            acc.z += av * wa.z;
            acc.w += av * wa.w;
        }
    }
    if (bias != nullptr) {
        float4 b = *(const float4*)(bias + j4);
        acc.x += b.x; acc.y += b.y; acc.z += b.z; acc.w += b.w;
    }
    if (doRelu) {
        acc.x = fmaxf(acc.x, 0.f);
        acc.y = fmaxf(acc.y, 0.f);
        acc.z = fmaxf(acc.z, 0.f);
        acc.w = fmaxf(acc.w, 0.f);
    }
    *(float4*)(out + (size_t)row * DIM + j4) = acc;
}

// ---------------------------------------------------------------------------
// Readout: batch sorted, NGR=32 graphs. Block binary-searches its segment.
__global__ __launch_bounds__(256) void readout_kernel(
    const float* __restrict__ xr, const int* __restrict__ batch,
    float* __restrict__ gsum, int nrows)
{
    __shared__ float lds[256 * 4];
    int g = blockIdx.x / RCHUNK;
    int chunk = blockIdx.x % RCHUNK;
    int lo = lbound(batch, nrows, g);
    int hi = lbound(batch, nrows, g + 1);
    int len = hi - lo;
    if (len == 0) return;
    int per = (len + RCHUNK - 1) / RCHUNK;
    int r0 = lo + chunk * per;
    int r1 = min(r0 + per, hi);

    int t = threadIdx.x;
    int c4 = (t & 31) << 2;
    int rsub = t >> 5;

    float4 acc = make_float4(0.f, 0.f, 0.f, 0.f);
    for (int r = r0 + rsub; r < r1; r += 8) {
        float4 v = *(const float4*)(xr + (size_t)r * DIM + c4);
        acc.x += v.x; acc.y += v.y; acc.z += v.z; acc.w += v.w;
    }
    *(float4*)(lds + t * 4) = acc;
    __syncthreads();
    if (rsub == 0) {
        float4 s = make_float4(0.f, 0.f, 0.f, 0.f);
        #pragma unroll
        for (int j = 0; j < 8; ++j) {
            float4 v = *(const float4*)(lds + (j * 32 + t) * 4);
            s.x += v.x; s.y += v.y; s.z += v.z; s.w += v.w;
        }
        atomicAdd(&gsum[(size_t)g * DIM + c4 + 0], s.x);
        atomicAdd(&gsum[(size_t)g * DIM + c4 + 1], s.y);
        atomicAdd(&gsum[(size_t)g * DIM + c4 + 2], s.z);
        atomicAdd(&gsum[(size_t)g * DIM + c4 + 3], s.w);
    }
}

__global__ __launch_bounds__(256) void finalize_kernel(
    const float* __restrict__ gsum, const int* __restrict__ batch,
    float* __restrict__ out, int nrows)
{
    int idx = blockIdx.x * 256 + threadIdx.x;
    if (idx >= NGR * DIM) return;
    int g = idx >> 7;
    int lo = lbound(batch, nrows, g);
    int hi = lbound(batch, nrows, g + 1);
    float c = fmaxf((float)(hi - lo), 1.f);
    out[idx] = gsum[idx] / c;
}

// ---------------------------------------------------------------------------
extern "C" void kernel_launch(void* const* d_in, const int* in_sizes, int n_in,
                              void* d_out, int out_size, void* d_ws, size_t ws_size,
                              hipStream_t stream)
{
    const float* x_real    = (const float*)d_in[0];
    const float* x_virtual = (const float*)d_in[1];
    const float* W_root    = (const float*)d_in[2];
    const float* W_nbr     = (const float*)d_in[3];
    const float* bias      = (const float*)d_in[4];
    const int*   edge_rr   = (const int*)d_in[5];   // [2, E_RR]
    const int*   edge_rv   = (const int*)d_in[6];   // [2, N_R] row0=arange row1=vmap
    const int*   edge_vr   = (const int*)d_in[7];   // [2, N_R] row0=vmap  row1=arange
    const int*   batch     = (const int*)d_in[8];   // [N_R] sorted

    float* out = (float*)d_out;                     // [N_R*DIM] + [NGR*DIM]

    // ---- workspace layout ----
    float* ws   = (float*)d_ws;
    float* Arv  = ws;                               // N_V*DIM
    float* Tv   = Arv  + (size_t)N_V * DIM;
    float* xv_a = Tv   + (size_t)N_V * DIM;
    float* xv_b = xv_a + (size_t)N_V * DIM;
    float* bc   = xv_b + (size_t)N_V * DIM;         // NLAY*DIM
    float* gsum = bc   + (size_t)NLAY * DIM;        // NGR*DIM
    ushort* xrb_in = (ushort*)(gsum + NGR * DIM);   // N_R*DIM bf16
    ushort* xrb_a  = xrb_in + (size_t)N_R * DIM;
    ushort* WT     = xrb_a  + (size_t)N_R * DIM;    // NLAY*128*256 bf16
    int* iws       = (int*)(WT + (size_t)NLAY * DIM * 2 * DIM);
    int* rowptr_rr = iws;                           // N_R+1
    int* col_rr    = rowptr_rr + N_R + 1;           // E_RR
    int* cnt_v     = col_rr + E_RR;                 // N_V
    int* rowptr_rv = cnt_v + N_V;                   // N_V+1
    int* cursor_rv = rowptr_rv + N_V + 1;           // N_V
    int* col_rv    = cursor_rv + N_V;               // N_R
    int* incl      = col_rv + N_R;                  // max(N_V, NBUK)
    int* bsum      = incl + N_V;                    // 256
    int* cnt2d     = bsum + 256;                    // NCHK*NBUK
    int* rel2d     = cnt2d + NCHK * NBUK;           // NCHK*NBUK
    int* tot       = rel2d + NCHK * NBUK;           // NBUK
    int* bstart    = tot + NBUK;                    // NBUK+1
    int* bcur      = bstart + NBUK + 1;             // NBUK (dummy)
    unsigned* ebuf = (unsigned*)(bcur + NBUK);      // E_RR

    const int* rr_src = edge_rr;
    const int* rr_dst = edge_rr + E_RR;
    const int* rv_src = edge_rv;
    const int* rv_dst = edge_rv + N_R;

    // ---- rr CSR via LDS-bucket sort (no device-scope atomics) ----
    bkt_count_kernel<<<NCHK, 256, 0, stream>>>(rr_dst, cnt2d);
    bkt_prefix_kernel<<<NBUK, 64, 0, stream>>>(cnt2d, rel2d, tot);
    scan1_kernel<<<(NBUK + 255) / 256, 256, 0, stream>>>(tot, NBUK, incl, bsum);
    scan2_kernel<<<1, 256, 0, stream>>>(bsum, (NBUK + 255) / 256);
    scan3_kernel<<<(NBUK + 255) / 256, 256, 0, stream>>>(tot, incl, bsum, NBUK, E_RR,
                                                         bstart, bcur);
    bkt_scatter_kernel<<<NCHK, 256, 0, stream>>>(rr_src, rr_dst, rel2d, bstart, ebuf);
    bkt_fine_kernel<<<NBUK, 256, 0, stream>>>(ebuf, bstart, rowptr_rr, col_rr);

    // ---- rv CSR (small): hist -> scan -> fill ----
    const int nbV = (N_V + 255) / 256;
    hipMemsetAsync(cnt_v, 0, (size_t)N_V * sizeof(int), stream);
    hist_kernel<<<(N_R + 255) / 256, 256, 0, stream>>>(rv_dst, N_R, cnt_v);
    scan1_kernel<<<nbV, 256, 0, stream>>>(cnt_v, N_V, incl, bsum);
    scan2_kernel<<<1, 256, 0, stream>>>(bsum, nbV);
    scan3_kernel<<<nbV, 256, 0, stream>>>(cnt_v, incl, bsum, N_V, N_R,
                                          rowptr_rv, cursor_rv);
    fill_kernel<<<(N_R + 255) / 256, 256, 0, stream>>>(rv_src, rv_dst, N_R, cursor_rv, col_rv);

    // weights/bias prep + input conversion
    build_wt_kernel<<<(NLAY * DIM * 2 * DIM + 255) / 256, 256, 0, stream>>>(W_root, W_nbr, WT);
    combine_b_kernel<<<(NLAY * DIM + 255) / 256, 256, 0, stream>>>(bias, bc);
    conv_bf16_kernel<<<(N_R * DIM / 4 + 255) / 256, 256, 0, stream>>>(x_real, xrb_in, N_R * DIM / 4);

    const ushort* cur_xrb = xrb_in;
    const float*  cur_xv  = x_virtual;

    for (int l = 0; l < NLAY; ++l) {
        const float* Wn1 = W_nbr + ((size_t)l * 3 + 1) * DIM * DIM;  // r->v nbr
        const float* Wn2 = W_nbr + ((size_t)l * 3 + 2) * DIM * DIM;  // v->r nbr
        const float* Wr1 = W_root + ((size_t)l * 3 + 1) * DIM * DIM; // v root
        const float* b1  = bias + ((size_t)l * 3 + 1) * DIM;

        // T_v = x_v @ Wn2 (fp32) — needed by fused epilogue
        gemm_kernel<<<(N_V + 7) / 8, 256, 0, stream>>>(
            cur_xv, Wn2, nullptr, nullptr, nullptr, Tv, N_V, 0);

        // x_r_new = relu( [x_r | gather(x_r)] @ WT_l + Tv[vmap] + bc_l )
        ushort* xrb_out = (l == NLAY - 1) ? nullptr : ((l & 1) ? xrb_in : xrb_a);
        float*  outF    = (l == NLAY - 1) ? out : nullptr;
        fused_layer_kernel<<<(N_R + 31) / 32, 256, 0, stream>>>(
            rowptr_rr, col_rr, cur_xrb, WT + (size_t)l * DIM * 2 * DIM,
            Tv, edge_vr, bc + (size_t)l * DIM, outF, xrb_out, N_R);

        if (l < NLAY - 1) {
            // A_rv[v] = sum x_r[r] over r with vmap[r]=v (fp32, layer input)
            agg_kernel<<<(N_V * 64 + 255) / 256, 256, 0, stream>>>(
                rowptr_rv, col_rv, cur_xrb, Arv, N_V);
            // x_v_new = relu( x_v @ Wr1 + A_rv @ Wn1 + b1 )
            float* xv_out = (l & 1) ? xv_b : xv_a;
            gemm_kernel<<<(N_V + 7) / 8, 256, 0, stream>>>(
                cur_xv, Wr1, Arv, Wn1, b1, xv_out, N_V, 1);
            cur_xv = xv_out;
        }
        cur_xrb = xrb_out;
    }

    // readout: mean over real nodes per graph (binary-search segments)
    hipMemsetAsync(gsum, 0, (size_t)NGR * DIM * sizeof(float), stream);
    readout_kernel<<<NGR * RCHUNK, 256, 0, stream>>>(out, batch, gsum, N_R);
    finalize_kernel<<<(NGR * DIM + 255) / 256, 256, 0, stream>>>(
        gsum, batch, out + (size_t)N_R * DIM, N_R);
}

// Round 9
// 375.636 us; speedup vs baseline: 13.6249x; 1.0872x over previous
//
#include <hip/hip_runtime.h>
#include <hip/hip_bf16.h>

// Problem constants (fixed by the reference setup_inputs()):
#define N_R   50000
#define N_V   2000
#define DIM   128
#define E_RR  800000
#define NLAY  3
#define NGR   32
#define RCHUNK 16   // readout chunks per graph

// bucket-CSR constants: bucket = dst>>7 (128 dsts/bucket), chunk = 2048 edges
#define BUKD  128
#define NBUK  391   // ceil(50000/128)
#define CHKE  2048
#define NCHK  391   // ceil(800000/2048)

typedef __attribute__((ext_vector_type(8))) short bf16x8;
typedef __attribute__((ext_vector_type(4))) float f32x4;

__device__ __forceinline__ ushort f2bf(float f) {
    unsigned u = __builtin_bit_cast(unsigned, f);
    unsigned r = (u + 0x7fffu + ((u >> 16) & 1u)) >> 16;   // RNE
    return (ushort)r;
}
__device__ __forceinline__ float bf2f(ushort h) {
    unsigned u = ((unsigned)h) << 16;
    return __builtin_bit_cast(float, u);
}
__device__ __forceinline__ int lbound(const int* __restrict__ a, int n, int key) {
    int lo = 0, hi = n;
    while (lo < hi) { int mid = (lo + hi) >> 1; if (a[mid] < key) lo = mid + 1; else hi = mid; }
    return lo;
}

// ---------------------------------------------------------------------------
__global__ __launch_bounds__(256) void hist_kernel(
    const int* __restrict__ dst, int n, int* __restrict__ cnt)
{
    int i = blockIdx.x * 256 + threadIdx.x;
    if (i < n) atomicAdd(&cnt[dst[i]], 1);
}

// single-block exclusive scan (n arbitrary, looped in 256-chunks)
__global__ __launch_bounds__(256) void scan_single_kernel(
    const int* __restrict__ cnt, int n, int nedges,
    int* __restrict__ rowptr, int* __restrict__ cursor)
{
    __shared__ int lds[256];
    __shared__ int carry;
    int t = threadIdx.x;
    if (t == 0) carry = 0;
    __syncthreads();
    for (int base = 0; base < n; base += 256) {
        int i = base + t;
        int v = (i < n) ? cnt[i] : 0;
        lds[t] = v;
        __syncthreads();
        #pragma unroll
        for (int off = 1; off < 256; off <<= 1) {
            int u = (t >= off) ? lds[t - off] : 0;
            __syncthreads();
            lds[t] += u;
            __syncthreads();
        }
        int excl = carry + lds[t] - v;
        if (i < n) {
            rowptr[i] = excl;
            if (cursor) cursor[i] = excl;
        }
        __syncthreads();
        if (t == 255) carry += lds[255];
        __syncthreads();
    }
    if (t == 0) rowptr[n] = nedges;
}

__global__ __launch_bounds__(256) void fill_kernel(
    const int* __restrict__ src, const int* __restrict__ dst, int n,
    int* __restrict__ cursor, int* __restrict__ col)
{
    int i = blockIdx.x * 256 + threadIdx.x;
    if (i < n) {
        int p = atomicAdd(&cursor[dst[i]], 1);
        col[p] = src[i];
    }
}

// ---------------------------------------------------------------------------
// Bucket-CSR build for the big rr relation (LDS atomics only).
__global__ __launch_bounds__(256) void bkt_count_kernel(
    const int* __restrict__ dst, int* __restrict__ cnt2d)
{
    __shared__ int h[NBUK];
    int t = threadIdx.x, c = blockIdx.x;
    for (int i = t; i < NBUK; i += 256) h[i] = 0;
    __syncthreads();
    int e0 = c * CHKE, e1 = min(e0 + CHKE, E_RR);
    for (int e = e0 + t; e < e1; e += 256) atomicAdd(&h[dst[e] >> 7], 1);
    __syncthreads();
    for (int i = t; i < NBUK; i += 256) cnt2d[(size_t)c * NBUK + i] = h[i];
}

__global__ __launch_bounds__(64) void bkt_prefix_kernel(
    const int* __restrict__ cnt2d, int* __restrict__ rel2d, int* __restrict__ tot)
{
    int b = blockIdx.x, lane = threadIdx.x;
    int base = 0;
    for (int c0 = 0; c0 < NCHK; c0 += 64) {
        int c = c0 + lane;
        int v = (c < NCHK) ? cnt2d[(size_t)c * NBUK + b] : 0;
        int s = v;
        #pragma unroll
        for (int off = 1; off < 64; off <<= 1) {
            int u = __shfl_up(s, off);
            if (lane >= off) s += u;
        }
        if (c < NCHK) rel2d[(size_t)c * NBUK + b] = base + s - v;
        base += __shfl(s, 63);
    }
    if (lane == 0) tot[b] = base;
}

__global__ __launch_bounds__(256) void bkt_scatter_kernel(
    const int* __restrict__ src, const int* __restrict__ dst,
    const int* __restrict__ rel2d, const int* __restrict__ bstart,
    unsigned* __restrict__ ebuf)
{
    __shared__ int cur[NBUK];
    int t = threadIdx.x, c = blockIdx.x;
    for (int i = t; i < NBUK; i += 256)
        cur[i] = bstart[i] + rel2d[(size_t)c * NBUK + i];
    __syncthreads();
    int e0 = c * CHKE, e1 = min(e0 + CHKE, E_RR);
    for (int e = e0 + t; e < e1; e += 256) {
        int d = dst[e];
        int p = atomicAdd(&cur[d >> 7], 1);
        ebuf[p] = ((unsigned)d << 16) | (unsigned)src[e];
    }
}

__global__ __launch_bounds__(256) void bkt_fine_kernel(
    const unsigned* __restrict__ ebuf, const int* __restrict__ bstart,
    int* __restrict__ rowptr, int* __restrict__ col)
{
    __shared__ int cnt[BUKD];
    __shared__ int sc[BUKD];
    __shared__ int cur[BUKD];
    int b = blockIdx.x, t = threadIdx.x;
    int s0 = bstart[b], s1 = bstart[b + 1];
    if (t < BUKD) cnt[t] = 0;
    __syncthreads();
    for (int e = s0 + t; e < s1; e += 256)
        atomicAdd(&cnt[(ebuf[e] >> 16) & (BUKD - 1)], 1);
    __syncthreads();
    if (t < BUKD) sc[t] = cnt[t];
    __syncthreads();
    #pragma unroll
    for (int off = 1; off < BUKD; off <<= 1) {
        int v = (t < BUKD && t >= off) ? sc[t - off] : 0;
        __syncthreads();
        if (t < BUKD) sc[t] += v;
        __syncthreads();
    }
    if (t < BUKD) {
        int ex = sc[t] - cnt[t];
        int d = b * BUKD + t;
        if (d < N_R) rowptr[d] = s0 + ex;
        cur[t] = ex;
    }
    if (b == NBUK - 1 && t == 0) rowptr[N_R] = E_RR;
    __syncthreads();
    for (int e = s0 + t; e < s1; e += 256) {
        unsigned pk = ebuf[e];
        int p = atomicAdd(&cur[(pk >> 16) & (BUKD - 1)], 1);
        col[s0 + p] = (int)(pk & 0xffffu);
    }
}

// ---------------------------------------------------------------------------
__global__ __launch_bounds__(256) void conv_bf16_kernel(
    const float* __restrict__ in, ushort* __restrict__ out, int n4)
{
    int i = blockIdx.x * 256 + threadIdx.x;
    if (i >= n4) return;
    float4 v = *(const float4*)(in + (size_t)i * 4);
    ushort4 o;
    o.x = f2bf(v.x); o.y = f2bf(v.y); o.z = f2bf(v.z); o.w = f2bf(v.w);
    *(ushort4*)(out + (size_t)i * 4) = o;
}

// WT[l][n][k] : k<128 -> Wroot[l,0,k,n]+Wroot[l,2,k,n] ; k>=128 -> Wnbr[l,0,k-128,n]
__global__ __launch_bounds__(256) void build_wt_kernel(
    const float* __restrict__ Wroot, const float* __restrict__ Wnbr,
    ushort* __restrict__ WT)
{
    int idx = blockIdx.x * 256 + threadIdx.x;
    if (idx >= NLAY * DIM * 2 * DIM) return;
    int k = idx & 255;
    int n = (idx >> 8) & 127;
    int l = idx >> 15;
    float v;
    if (k < DIM) {
        const float* base = Wroot + (size_t)l * 3 * DIM * DIM;
        v = base[(size_t)k * DIM + n] + base[(size_t)(2 * DIM + k) * DIM + n];
    } else {
        v = Wnbr[((size_t)l * 3 * DIM + (k - DIM)) * DIM + n];
    }
    WT[idx] = f2bf(v);
}

__global__ __launch_bounds__(256) void combine_b_kernel(
    const float* __restrict__ bias, float* __restrict__ bc)
{
    int idx = blockIdx.x * 256 + threadIdx.x;
    if (idx >= NLAY * DIM) return;
    int l = idx / DIM;
    int rest = idx - l * DIM;
    const float* base = bias + (size_t)l * 3 * DIM;
    bc[idx] = base[rest] + base[2 * DIM + rest];
}

// ---------------------------------------------------------------------------
// Fused virtual-node layer: per v-row computes
//   Tv[v]      = xv[v] @ Wn2                       (always)
//   xv_next[v] = relu(xv[v]@Wr1 + Arv[v]@Wn1 + b1) (doNext)
// where Arv[v] = sum_{r: vmap[r]=v} Xr[r]  (bf16 gather, LDS-staged).
// Block: 256 thr = 8 rows x 32 thr (4 cols each). N_V%8==0.
__global__ __launch_bounds__(256) void vlayer_kernel(
    const int* __restrict__ rowptr, const int* __restrict__ col,
    const ushort* __restrict__ Xr, const float* __restrict__ xv,
    const float* __restrict__ Wn2, const float* __restrict__ Wr1,
    const float* __restrict__ Wn1, const float* __restrict__ b1,
    float* __restrict__ Tv, float* __restrict__ xv_next, int doNext)
{
    __shared__ float arv_s[8 * DIM];
    int t = threadIdx.x;
    int lr = t >> 5;
    int j4 = (t & 31) << 2;
    int row = blockIdx.x * 8 + lr;

    if (doNext) {
        int beg = rowptr[row], end = rowptr[row + 1];
        float a0 = 0.f, a1 = 0.f, a2 = 0.f, a3 = 0.f;
        int e = beg;
        for (; e + 3 < end; e += 4) {
            ushort4 u0 = *(const ushort4*)(Xr + (size_t)col[e + 0] * DIM + j4);
            ushort4 u1 = *(const ushort4*)(Xr + (size_t)col[e + 1] * DIM + j4);
            ushort4 u2 = *(const ushort4*)(Xr + (size_t)col[e + 2] * DIM + j4);
            ushort4 u3 = *(const ushort4*)(Xr + (size_t)col[e + 3] * DIM + j4);
            a0 += bf2f(u0.x) + bf2f(u1.x) + bf2f(u2.x) + bf2f(u3.x);
            a1 += bf2f(u0.y) + bf2f(u1.y) + bf2f(u2.y) + bf2f(u3.y);
            a2 += bf2f(u0.z) + bf2f(u1.z) + bf2f(u2.z) + bf2f(u3.z);
            a3 += bf2f(u0.w) + bf2f(u1.w) + bf2f(u2.w) + bf2f(u3.w);
        }
        for (; e < end; ++e) {
            ushort4 u0 = *(const ushort4*)(Xr + (size_t)col[e] * DIM + j4);
            a0 += bf2f(u0.x); a1 += bf2f(u0.y); a2 += bf2f(u0.z); a3 += bf2f(u0.w);
        }
        arv_s[lr * DIM + j4 + 0] = a0;
        arv_s[lr * DIM + j4 + 1] = a1;
        arv_s[lr * DIM + j4 + 2] = a2;
        arv_s[lr * DIM + j4 + 3] = a3;
        __syncthreads();
    }

    const float* arow = xv + (size_t)row * DIM;
    float4 tacc = make_float4(0.f, 0.f, 0.f, 0.f);
    float4 nacc = make_float4(0.f, 0.f, 0.f, 0.f);
    if (doNext) {
        #pragma unroll 4
        for (int k = 0; k < DIM; ++k) {
            float av = arow[k];
            float bv = arv_s[lr * DIM + k];
            float4 w2 = *(const float4*)(Wn2 + (size_t)k * DIM + j4);
            float4 wr = *(const float4*)(Wr1 + (size_t)k * DIM + j4);
            float4 wn = *(const float4*)(Wn1 + (size_t)k * DIM + j4);
            tacc.x += av * w2.x; tacc.y += av * w2.y;
            tacc.z += av * w2.z; tacc.w += av * w2.w;
            nacc.x += av * wr.x + bv * wn.x;
            nacc.y += av * wr.y + bv * wn.y;
            nacc.z += av * wr.z + bv * wn.z;
            nacc.w += av * wr.w + bv * wn.w;
        }
    } else {
        #pragma unroll 8
        for (int k = 0; k < DIM; ++k) {
            float av = arow[k];
            float4 w2 = *(const float4*)(Wn2 + (size_t)k * DIM + j4);
            tacc.x += av * w2.x; tacc.y += av * w2.y;
            tacc.z += av * w2.z; tacc.w += av * w2.w;
        }
    }
    *(float4*)(Tv + (size_t)row * DIM + j4) = tacc;
    if (doNext) {
        float4 b = *(const float4*)(b1 + j4);
        nacc.x = fmaxf(nacc.x + b.x, 0.f);
        nacc.y = fmaxf(nacc.y + b.y, 0.f);
        nacc.z = fmaxf(nacc.z + b.z, 0.f);
        nacc.w = fmaxf(nacc.w + b.w, 0.f);
        *(float4*)(xv_next + (size_t)row * DIM + j4) = nacc;
    }
}

// ---------------------------------------------------------------------------
// FUSED real-node layer kernel (128 thr = 2 waves, 16 rows/block):
//   A2[r] = sum_{e in CSR row r} X[col[e]]   (gather, 4-edge unrolled, LDS)
//   C[r]  = relu( [X[r] | A2[r]] @ WT + Tv[vmap[r]] + bias )
__global__ __launch_bounds__(128) void fused_layer_kernel(
    const int* __restrict__ rowptr, const int* __restrict__ col,
    const ushort* __restrict__ X,  const ushort* __restrict__ WT,
    const float* __restrict__ Tv,  const int* __restrict__ vmap,
    const float* __restrict__ bias,
    float* __restrict__ outF, ushort* __restrict__ outB, int M)
{
    __shared__ ushort a2[16 * DIM];          // 4 KB, swizzled rows
    int t = threadIdx.x;

    // ---- phase 0: prefetch A1 fragments + vmap
    int wave = t >> 6, lane = t & 63;        // wave = col half (0..1)
    int rlo = lane & 15, hi = lane >> 4;
    int row0 = blockIdx.x * 16;
    int arowc = min(row0 + rlo, M - 1);
    bf16x8 afr[8];
    #pragma unroll
    for (int j = 0; j < 4; ++j)
        afr[j] = *(const bf16x8*)(X + (size_t)arowc * DIM + 32 * j + 8 * hi);
    int vr[4];
    #pragma unroll
    for (int i = 0; i < 4; ++i)
        vr[i] = vmap[min(row0 + 4 * hi + i, M - 1)];

    // ---- phase 1: gather A2 rows into LDS (8 groups x 16 lanes, 4-edge MLP)
    int g = t >> 4;                          // 0..7
    int li = t & 15;
    for (int rr = g; rr < 16; rr += 8) {
        int drow = min(row0 + rr, M - 1);
        int beg = rowptr[drow], end = rowptr[drow + 1];
        float acc[8] = {0.f,0.f,0.f,0.f,0.f,0.f,0.f,0.f};
        int e = beg;
        for (; e + 3 < end; e += 4) {
            bf16x8 v0 = *(const bf16x8*)(X + (size_t)col[e + 0] * DIM + li * 8);
            bf16x8 v1 = *(const bf16x8*)(X + (size_t)col[e + 1] * DIM + li * 8);
            bf16x8 v2 = *(const bf16x8*)(X + (size_t)col[e + 2] * DIM + li * 8);
            bf16x8 v3 = *(const bf16x8*)(X + (size_t)col[e + 3] * DIM + li * 8);
            #pragma unroll
            for (int q = 0; q < 8; ++q)
                acc[q] += (bf2f((ushort)v0[q]) + bf2f((ushort)v1[q]))
                        + (bf2f((ushort)v2[q]) + bf2f((ushort)v3[q]));
        }
        for (; e < end; ++e) {
            bf16x8 v0 = *(const bf16x8*)(X + (size_t)col[e] * DIM + li * 8);
            #pragma unroll
            for (int q = 0; q < 8; ++q) acc[q] += bf2f((ushort)v0[q]);
        }
        bf16x8 pk;
        #pragma unroll
        for (int q = 0; q < 8; ++q) pk[q] = (short)f2bf(acc[q]);
        int byte = rr * 256 + ((li * 16) ^ ((rr & 7) << 4));
        *(bf16x8*)((char*)a2 + byte) = pk;
    }
    __syncthreads();

    // ---- phase 2: A2 fragments from LDS, MFMA, fused epilogue
    #pragma unroll
    for (int jj = 0; jj < 4; ++jj) {
        int byte = rlo * 256 + ((64 * jj + 16 * hi) ^ ((rlo & 7) << 4));
        afr[4 + jj] = *(const bf16x8*)((const char*)a2 + byte);
    }

    f32x4 acc[4];
    #pragma unroll
    for (int n = 0; n < 4; ++n) acc[n] = (f32x4){0.f, 0.f, 0.f, 0.f};

    #pragma unroll
    for (int n = 0; n < 4; ++n) {
        int nt = wave * 4 + n;               // n-tile 0..7
        const ushort* wrow = WT + (size_t)(nt * 16 + rlo) * (2 * DIM);
        #pragma unroll
        for (int j = 0; j < 8; ++j) {
            bf16x8 bfr = *(const bf16x8*)(wrow + 32 * j + 8 * hi);
            acc[n] = __builtin_amdgcn_mfma_f32_16x16x32_bf16(afr[j], bfr, acc[n], 0, 0, 0);
        }
    }

    // epilogue: C row = row0 + 4*hi + i, col = (wave*4+n)*16 + rlo
    #pragma unroll
    for (int n = 0; n < 4; ++n) {
        int ncol = (wave * 4 + n) * 16 + rlo;
        float bv = bias[ncol];
        #pragma unroll
        for (int i = 0; i < 4; ++i) {
            int orow = row0 + 4 * hi + i;
            if (orow >= M) continue;
            float v = acc[n][i] + bv + Tv[(size_t)vr[i] * DIM + ncol];
            v = fmaxf(v, 0.f);
            if (outF) outF[(size_t)orow * DIM + ncol] = v;
            if (outB) outB[(size_t)orow * DIM + ncol] = f2bf(v);
        }
    }
}

// ---------------------------------------------------------------------------
// Readout: batch sorted, NGR=32 graphs. Block binary-searches its segment.
__global__ __launch_bounds__(256) void readout_kernel(
    const float* __restrict__ xr, const int* __restrict__ batch,
    float* __restrict__ gsum, int nrows)
{
    __shared__ float lds[256 * 4];
    int g = blockIdx.x / RCHUNK;
    int chunk = blockIdx.x % RCHUNK;
    int lo = lbound(batch, nrows, g);
    int hi = lbound(batch, nrows, g + 1);
    int len = hi - lo;
    if (len == 0) return;
    int per = (len + RCHUNK - 1) / RCHUNK;
    int r0 = lo + chunk * per;
    int r1 = min(r0 + per, hi);

    int t = threadIdx.x;
    int c4 = (t & 31) << 2;
    int rsub = t >> 5;

    float4 acc = make_float4(0.f, 0.f, 0.f, 0.f);
    for (int r = r0 + rsub; r < r1; r += 8) {
        float4 v = *(const float4*)(xr + (size_t)r * DIM + c4);
        acc.x += v.x; acc.y += v.y; acc.z += v.z; acc.w += v.w;
    }
    *(float4*)(lds + t * 4) = acc;
    __syncthreads();
    if (rsub == 0) {
        float4 s = make_float4(0.f, 0.f, 0.f, 0.f);
        #pragma unroll
        for (int j = 0; j < 8; ++j) {
            float4 v = *(const float4*)(lds + (j * 32 + t) * 4);
            s.x += v.x; s.y += v.y; s.z += v.z; s.w += v.w;
        }
        atomicAdd(&gsum[(size_t)g * DIM + c4 + 0], s.x);
        atomicAdd(&gsum[(size_t)g * DIM + c4 + 1], s.y);
        atomicAdd(&gsum[(size_t)g * DIM + c4 + 2], s.z);
        atomicAdd(&gsum[(size_t)g * DIM + c4 + 3], s.w);
    }
}

__global__ __launch_bounds__(256) void finalize_kernel(
    const float* __restrict__ gsum, const int* __restrict__ batch,
    float* __restrict__ out, int nrows)
{
    int idx = blockIdx.x * 256 + threadIdx.x;
    if (idx >= NGR * DIM) return;
    int g = idx >> 7;
    int lo = lbound(batch, nrows, g);
    int hi = lbound(batch, nrows, g + 1);
    float c = fmaxf((float)(hi - lo), 1.f);
    out[idx] = gsum[idx] / c;
}

// ---------------------------------------------------------------------------
extern "C" void kernel_launch(void* const* d_in, const int* in_sizes, int n_in,
                              void* d_out, int out_size, void* d_ws, size_t ws_size,
                              hipStream_t stream)
{
    const float* x_real    = (const float*)d_in[0];
    const float* x_virtual = (const float*)d_in[1];
    const float* W_root    = (const float*)d_in[2];
    const float* W_nbr     = (const float*)d_in[3];
    const float* bias      = (const float*)d_in[4];
    const int*   edge_rr   = (const int*)d_in[5];   // [2, E_RR]
    const int*   edge_rv   = (const int*)d_in[6];   // [2, N_R] row0=arange row1=vmap
    const int*   edge_vr   = (const int*)d_in[7];   // [2, N_R] row0=vmap  row1=arange
    const int*   batch     = (const int*)d_in[8];   // [N_R] sorted

    float* out = (float*)d_out;                     // [N_R*DIM] + [NGR*DIM]

    // ---- workspace layout ----
    float* ws   = (float*)d_ws;
    float* Tv   = ws;                               // N_V*DIM
    float* xv_a = Tv   + (size_t)N_V * DIM;
    float* xv_b = xv_a + (size_t)N_V * DIM;
    float* bc   = xv_b + (size_t)N_V * DIM;         // NLAY*DIM
    float* gsum = bc   + (size_t)NLAY * DIM;        // NGR*DIM
    ushort* xrb_in = (ushort*)(gsum + NGR * DIM);   // N_R*DIM bf16
    ushort* xrb_a  = xrb_in + (size_t)N_R * DIM;
    ushort* WT     = xrb_a  + (size_t)N_R * DIM;    // NLAY*128*256 bf16
    int* iws       = (int*)(WT + (size_t)NLAY * DIM * 2 * DIM);
    int* rowptr_rr = iws;                           // N_R+1
    int* col_rr    = rowptr_rr + N_R + 1;           // E_RR
    int* cnt_v     = col_rr + E_RR;                 // N_V
    int* rowptr_rv = cnt_v + N_V;                   // N_V+1
    int* cursor_rv = rowptr_rv + N_V + 1;           // N_V
    int* col_rv    = cursor_rv + N_V;               // N_R
    int* cnt2d     = col_rv + N_R;                  // NCHK*NBUK
    int* rel2d     = cnt2d + NCHK * NBUK;           // NCHK*NBUK
    int* tot       = rel2d + NCHK * NBUK;           // NBUK
    int* bstart    = tot + NBUK;                    // NBUK+1
    unsigned* ebuf = (unsigned*)(bstart + NBUK + 1);// E_RR

    const int* rr_src = edge_rr;
    const int* rr_dst = edge_rr + E_RR;
    const int* rv_src = edge_rv;
    const int* rv_dst = edge_rv + N_R;

    // ---- rr CSR via LDS-bucket sort (no device-scope atomics) ----
    bkt_count_kernel<<<NCHK, 256, 0, stream>>>(rr_dst, cnt2d);
    bkt_prefix_kernel<<<NBUK, 64, 0, stream>>>(cnt2d, rel2d, tot);
    scan_single_kernel<<<1, 256, 0, stream>>>(tot, NBUK, E_RR, bstart, nullptr);
    bkt_scatter_kernel<<<NCHK, 256, 0, stream>>>(rr_src, rr_dst, rel2d, bstart, ebuf);
    bkt_fine_kernel<<<NBUK, 256, 0, stream>>>(ebuf, bstart, rowptr_rr, col_rr);

    // ---- rv CSR (small): hist -> single-block scan -> fill ----
    hipMemsetAsync(cnt_v, 0, (size_t)N_V * sizeof(int), stream);
    hist_kernel<<<(N_R + 255) / 256, 256, 0, stream>>>(rv_dst, N_R, cnt_v);
    scan_single_kernel<<<1, 256, 0, stream>>>(cnt_v, N_V, N_R, rowptr_rv, cursor_rv);
    fill_kernel<<<(N_R + 255) / 256, 256, 0, stream>>>(rv_src, rv_dst, N_R, cursor_rv, col_rv);

    // weights/bias prep + input conversion
    build_wt_kernel<<<(NLAY * DIM * 2 * DIM + 255) / 256, 256, 0, stream>>>(W_root, W_nbr, WT);
    combine_b_kernel<<<(NLAY * DIM + 255) / 256, 256, 0, stream>>>(bias, bc);
    conv_bf16_kernel<<<(N_R * DIM / 4 + 255) / 256, 256, 0, stream>>>(x_real, xrb_in, N_R * DIM / 4);

    const ushort* cur_xrb = xrb_in;
    const float*  cur_xv  = x_virtual;

    for (int l = 0; l < NLAY; ++l) {
        const float* Wn1 = W_nbr + ((size_t)l * 3 + 1) * DIM * DIM;  // r->v nbr
        const float* Wn2 = W_nbr + ((size_t)l * 3 + 2) * DIM * DIM;  // v->r nbr
        const float* Wr1 = W_root + ((size_t)l * 3 + 1) * DIM * DIM; // v root
        const float* b1  = bias + ((size_t)l * 3 + 1) * DIM;

        int doNext = (l < NLAY - 1);
        float* xv_out = (l & 1) ? xv_b : xv_a;

        // Tv_l (+ xv_{l+1} if doNext) — uses layer-input Xr and xv
        vlayer_kernel<<<N_V / 8, 256, 0, stream>>>(
            rowptr_rv, col_rv, cur_xrb, cur_xv,
            Wn2, Wr1, Wn1, b1, Tv, xv_out, doNext);

        // x_r_new = relu( [x_r | gather(x_r)] @ WT_l + Tv[vmap] + bc_l )
        ushort* xrb_out = (l == NLAY - 1) ? nullptr : ((l & 1) ? xrb_in : xrb_a);
        float*  outF    = (l == NLAY - 1) ? out : nullptr;
        fused_layer_kernel<<<(N_R + 15) / 16, 128, 0, stream>>>(
            rowptr_rr, col_rr, cur_xrb, WT + (size_t)l * DIM * 2 * DIM,
            Tv, edge_vr, bc + (size_t)l * DIM, outF, xrb_out, N_R);

        if (doNext) cur_xv = xv_out;
        cur_xrb = xrb_out;
    }

    // readout: mean over real nodes per graph (binary-search segments)
    hipMemsetAsync(gsum, 0, (size_t)NGR * DIM * sizeof(float), stream);
    readout_kernel<<<NGR * RCHUNK, 256, 0, stream>>>(out, batch, gsum, N_R);
    finalize_kernel<<<(NGR * DIM + 255) / 256, 256, 0, stream>>>(
        gsum, batch, out + (size_t)N_R * DIM, N_R);
}